// Round 10
// baseline (282.542 us; speedup 1.0000x reference)
//
#include <hip/hip_runtime.h>
#include <stdint.h>

#pragma clang fp contract(off)

#define NN    300000
#define TOPK  6000u
#define KW    94
#define KPAD  6016
#define SORTN 8192
#define NCHUNK 16
#define CSZ   512
#define OUTK  300
#define RCAP  64
#define ELDS2 12288
#define NREP  8

// ---------------- workspace layout (bytes) ----------------
static constexpr size_t OFF_ROI    = 0;                                   // NN*16
static constexpr size_t OFF_KEY    = OFF_ROI + (size_t)NN * 16;           // NN*4
static constexpr size_t OFF_HIST16 = ((OFF_KEY + (size_t)NN * 4 + 255) & ~(size_t)255); // NREP*65536*4
static constexpr size_t OFF_HIST8  = OFF_HIST16 + (size_t)NREP * 65536 * 4; // 1 KB
static constexpr size_t OFF_SCAL   = OFF_HIST8 + 1024;                    // 256 B scalars
static constexpr size_t OFF_RCNT   = OFF_SCAL + 256;                      // KPAD*4 = 24064
static constexpr size_t ZERO_BYTES = (OFF_RCNT + (size_t)KPAD * 4) - OFF_HIST16;
static constexpr size_t OFF_HISTS  = OFF_RCNT + (size_t)KPAD * 4;         // 65536*4
static constexpr size_t OFF_SORT   = OFF_HISTS + 65536 * 4;               // SORTN*8
static constexpr size_t OFF_SELBOX = OFF_SORT + (size_t)SORTN * 8;        // KPAD*16
static constexpr size_t OFF_ROWS   = ((OFF_SELBOX + (size_t)KPAD * 16 + 255) & ~(size_t)255); // KPAD*RCAP*2

// scal[] layout: [0]=P16 bin, [1]=count_below16, [2]=T24 prefix, [3]=compact counter,
//                [4]=total valid count

__device__ __forceinline__ uint32_t score_key(float s) {
  uint32_t u = __float_as_uint(s);
  u = (u >> 31) ? ~u : (u | 0x80000000u);  // monotonic: ascending uint == ascending float
  return ~u;                               // invert: ascending uint == DESCENDING float
}

// bit-reversed histogram slot: consecutive bins -> distinct cache lines.
__device__ __forceinline__ uint32_t hslot(uint32_t b) { return __brev(b) >> 16; }

// ---------------- 1. decode + key + replicated 16-bit histogram ----------------
__global__ void k_decode(const float* __restrict__ cls, const float* __restrict__ reg,
                         const float* __restrict__ anchor, float4* __restrict__ roi,
                         uint32_t* __restrict__ key, uint32_t* __restrict__ hist16) {
  int i = blockIdx.x * blockDim.x + threadIdx.x;
  if (i >= NN) return;
  // softmax(cls)[1], bit-identical op sequence; exp(0)==1.0 exactly -> one f64 exp
  float c0 = cls[2 * i], c1 = cls[2 * i + 1];
  float m  = fmaxf(c0, c1);
  float a0 = c0 - m, a1 = c1 - m;          // one is exactly 0.0f
  float tn = fminf(a0, a1);
  float e  = (float)exp((double)tn);
  float e0 = (a0 == 0.0f) ? 1.0f : e;
  float e1 = (a1 == 0.0f) ? 1.0f : e;
  float s  = e1 / (e0 + e1);

  float4 a = ((const float4*)anchor)[i];
  float acx = (a.x + a.z) * 0.5f;
  float acy = (a.y + a.w) * 0.5f;
  float aw  = a.z - a.x;
  float ah  = a.w - a.y;
  float4 r = ((const float4*)reg)[i];
  float cx = r.x * aw + acx;
  float cy = r.y * ah + acy;
  float w  = (float)exp((double)r.z) * aw;
  float h  = (float)exp((double)r.w) * ah;
  float x1 = cx - w * 0.5f, y1 = cy - h * 0.5f;
  float x2 = cx + w * 0.5f, y2 = cy + h * 0.5f;
  x1 = fminf(fmaxf(x1, 0.0f), 1.0f);
  y1 = fminf(fmaxf(y1, 0.0f), 1.0f);
  x2 = fminf(fmaxf(x2, 0.0f), 1.0f);
  y2 = fminf(fmaxf(y2, 0.0f), 1.0f);
  float ws_ = x2 - x1, hs_ = y2 - y1;
  bool valid = (hs_ >= 0.001f) && (ws_ >= 0.001f);
  float msc = valid ? s : -__builtin_inff();
  uint32_t kk = score_key(msc);

  roi[i] = make_float4(x1, y1, x2, y2);
  key[i] = kk;
  // 8 histogram replicas (blockIdx&7): hottest line's serialized RMWs /8
  if (valid) atomicAdd(&hist16[((blockIdx.x & (NREP - 1)) << 16) + hslot(kk >> 16)], 1u);
}

// ---------------- 1b. reduce 8 replicas ----------------
__global__ void __launch_bounds__(256) k_hsum(const uint32_t* __restrict__ hist16,
                                              uint32_t* __restrict__ hists) {
  int i = blockIdx.x * 256 + threadIdx.x;  // 0..65535
  uint32_t s = 0;
#pragma unroll
  for (int r = 0; r < NREP; r++) s += hist16[(r << 16) + i];
  hists[i] = s;
}

// ---------------- 2. scan 65536-bin histogram (bit-reversed layout) ----------------
__global__ void __launch_bounds__(1024) k_scan16(const uint32_t* __restrict__ hists,
                                                 int* __restrict__ scal) {
  __shared__ unsigned short hh[65536];   // 128 KB
  __shared__ uint32_t part[1024];
  int t = threadIdx.x;
  const uint4* h4 = (const uint4*)hists;
#pragma unroll
  for (int k = 0; k < 16; k++) {
    uint4 v = h4[k * 1024 + t];
    uint32_t base = 4 * (k * 1024 + t);   // permuted-space index
    hh[__brev(base + 0) >> 16] = (unsigned short)v.x;  // brev is an involution
    hh[__brev(base + 1) >> 16] = (unsigned short)v.y;
    hh[__brev(base + 2) >> 16] = (unsigned short)v.z;
    hh[__brev(base + 3) >> 16] = (unsigned short)v.w;
  }
  __syncthreads();
  uint32_t sum = 0;
  for (int b = 0; b < 64; b++) sum += hh[t * 64 + b];
  part[t] = sum;
  __syncthreads();
  for (int off = 1; off < 1024; off <<= 1) {
    uint32_t v = (t >= off) ? part[t - off] : 0;
    __syncthreads();
    part[t] += v;
    __syncthreads();
  }
  if (t == 1023) scal[4] = (int)part[1023];   // total valid count
  uint32_t excl = part[t] - sum;
  if (excl < TOPK && excl + sum >= TOPK) {
    uint32_t cum = excl;
    for (int b = 0; b < 64; b++) {
      uint32_t h = hh[t * 64 + b];
      if (cum < TOPK && cum + h >= TOPK) { scal[0] = t * 64 + b; scal[1] = (int)cum; break; }
      cum += h;
    }
  }
}

// ---------------- 3. 8-bit refinement histogram ----------------
__global__ void k_hist8(const uint32_t* __restrict__ key, const int* __restrict__ scal,
                        uint32_t* __restrict__ hist8) {
  int i = blockIdx.x * blockDim.x + threadIdx.x;
  if (i >= NN) return;
  uint32_t P = (uint32_t)scal[0];
  uint32_t kk = key[i];
  if ((kk >> 16) == P) atomicAdd(&hist8[(kk >> 8) & 0xFFu], 1u);
}

__global__ void __launch_bounds__(256) k_scan8(const uint32_t* __restrict__ hist8,
                                               int* __restrict__ scal) {
  __shared__ uint32_t part[256];
  int t = threadIdx.x;
  uint32_t h = hist8[t];
  part[t] = h;
  __syncthreads();
  for (int off = 1; off < 256; off <<= 1) {
    uint32_t v = (t >= off) ? part[t - off] : 0;
    __syncthreads();
    part[t] += v;
    __syncthreads();
  }
  uint32_t excl = part[t] - h;
  uint32_t cb = (uint32_t)scal[1];
  if (cb + excl < TOPK && cb + excl + h >= TOPK)
    scal[2] = (scal[0] << 8) | t;
}

// ---------------- 4. compact candidates (prefix24 <= T24) ----------------
__global__ void k_compact(const uint32_t* __restrict__ key, int* __restrict__ scal,
                          unsigned long long* __restrict__ sortbuf) {
  __shared__ int lcnt, lbase;
  int t = threadIdx.x;
  int i = blockIdx.x * blockDim.x + t;
  if (t == 0) lcnt = 0;
  __syncthreads();
  bool sel = false;
  uint32_t kk = 0;
  int my = 0;
  if (i < NN) {
    uint32_t T24 = (uint32_t)scal[2];
    kk = key[i];
    if ((kk >> 8) <= T24) { sel = true; my = atomicAdd(&lcnt, 1); }
  }
  __syncthreads();
  if (t == 0 && lcnt > 0) lbase = atomicAdd(&scal[3], lcnt);
  __syncthreads();
  if (sel) {
    int pos = lbase + my;
    if (pos < SORTN) sortbuf[pos] = (((unsigned long long)kk) << 32) | (uint32_t)i;
  }
}

// ---------------- 5a. per-chunk bitonic sort (16 blocks x 512 elems, in place) --------
__global__ void __launch_bounds__(256) k_sortA(unsigned long long* __restrict__ sortbuf) {
  __shared__ unsigned long long sm[CSZ];
  int t = threadIdx.x;
  unsigned long long* chunk = sortbuf + (size_t)blockIdx.x * CSZ;
  sm[t] = chunk[t];
  sm[t + 256] = chunk[t + 256];
  __syncthreads();
  for (int k = 2; k <= CSZ; k <<= 1) {
    for (int j = k >> 1; j > 0; j >>= 1) {
      int i1 = ((t & ~(j - 1)) << 1) | (t & (j - 1));
      int i2 = i1 | j;
      bool up = ((i1 & k) == 0);
      unsigned long long a = sm[i1], b = sm[i2];
      if ((a > b) == up) { sm[i1] = b; sm[i2] = a; }
      __syncthreads();
    }
  }
  chunk[t] = sm[t];
  chunk[t + 256] = sm[t + 256];
}

// ---------------- 5b. stable multi-merge rank + scatter top-6000 ----------------
__global__ void __launch_bounds__(256) k_sortB(const unsigned long long* __restrict__ sortbuf,
                                               const float4* __restrict__ roi,
                                               float4* __restrict__ selbox) {
  int g = blockIdx.x * 256 + threadIdx.x;   // 0..8191
  int c = g >> 9, p = g & (CSZ - 1);
  unsigned long long val = sortbuf[g];
  int rank = p;
  for (int c2 = 0; c2 < NCHUNK; c2++) {
    if (c2 == c) continue;
    const unsigned long long* base = sortbuf + ((size_t)c2 << 9);
    bool le = (c2 < c);                     // earlier chunk: count <=, later: count <
    int pos = 0;
#pragma unroll
    for (int s = CSZ; s > 0; s >>= 1) {
      if (pos + s <= CSZ) {
        unsigned long long v = base[pos + s - 1];
        if (le ? (v <= val) : (v < val)) pos += s;
      }
    }
    rank += pos;
  }
  if (rank < (int)TOPK) {
    selbox[rank] = roi[(uint32_t)val];
  } else if (rank < KPAD) {
    selbox[rank] = make_float4(0.f, 0.f, 0.f, 0.f);
  }
}

// ---------------- 6. suppression pairs -> per-row lists (row-major = i-sorted) -------
// rows[i][0..cnt): j's suppressed by i (j>i, IoU>0.7), both intra- and inter-chunk.
__global__ void __launch_bounds__(64) k_mask(const float4* __restrict__ selbox,
                                             uint32_t* __restrict__ rcnt,
                                             unsigned short* __restrict__ rows) {
  int bi = blockIdx.x, bj = blockIdx.y;
  if (bj < bi) return;
  int t = threadIdx.x;
  __shared__ float4 jb[64];
  __shared__ float  ja[64];
  int j0 = bj * 64;
  float4 cb = selbox[j0 + t];
  jb[t] = cb;
  ja[t] = (cb.z - cb.x) * (cb.w - cb.y);
  __syncthreads();
  int i = bi * 64 + t;
  unsigned long long word = 0;
  if (i < (int)TOPK) {
    float4 bi4 = selbox[i];
    float ai = (bi4.z - bi4.x) * (bi4.w - bi4.y);
    for (int jj = 0; jj < 64; jj++) {
      int j = j0 + jj;
      float4 bb = jb[jj];
      float ltx = fmaxf(bi4.x, bb.x), lty = fmaxf(bi4.y, bb.y);
      float rbx = fminf(bi4.z, bb.z), rby = fminf(bi4.w, bb.w);
      float wx = fmaxf(rbx - ltx, 0.0f), wy = fmaxf(rby - lty, 0.0f);
      float inter = wx * wy;
      float iou = inter / (ai + ja[jj] - inter + 1e-9f);
      if (iou > 0.7f && j > i && j < (int)TOPK) word |= (1ull << jj);
    }
  }
  if (word) {
    uint32_t n = (uint32_t)__popcll(word);
    uint32_t pos = atomicAdd(&rcnt[i], n);
    unsigned long long rem = word;
    while (rem && pos < RCAP) {
      int jj = (int)__builtin_ctzll(rem);
      rem &= rem - 1;
      rows[(size_t)i * RCAP + pos] = (unsigned short)(j0 + jj);
      pos++;
    }
  }
}

// ---------------- 7. greedy keep: E-scaled serial entry pass ----------------
// Exact greedy NMS == "for entries (i,j) ascending i: if keep[i]: clear keep[j]".
// Parallel prefix over 6016 row counts -> gather entries compacted into LDS
// (row-major order = globally i-sorted) -> wave 0 serial pass, keep bitmap in
// LANE REGISTERS (lane l owns words l and l+64); ~25 cyc/entry, no LDS/global
// in the dependency chain. Batch loads double-buffered.
__global__ void __launch_bounds__(256) k_seq(const uint32_t* __restrict__ rcnt,
                                             const unsigned short* __restrict__ rows,
                                             const int* __restrict__ scal,
                                             const float4* __restrict__ selbox,
                                             float* __restrict__ out) {
  __shared__ uint32_t elds[ELDS2];            // 48 KB
  __shared__ uint32_t wtot[4];
  __shared__ uint32_t totE_s;
  __shared__ uint32_t keep32[2 * KW];
  __shared__ uint32_t wcnt_s[KW];
  __shared__ uint32_t wrank[KW];
  __shared__ uint32_t carry_s;
  const int t = threadIdx.x, lane = t & 63, wv = t >> 6;

  // 1. per-thread segment of 24 rows: counts + local prefix (registers)
  uint32_t cnt[24], loc[24];
  uint32_t s = 0;
#pragma unroll
  for (int k = 0; k < 24; k++) {
    int r = t * 24 + k;
    uint32_t c = (r < KPAD) ? rcnt[r] : 0;
    c = (c > RCAP) ? RCAP : c;
    loc[k] = s; cnt[k] = c; s += c;
  }
  // 2. 256-thread exclusive scan of segment sums
  uint32_t pre = s;
#pragma unroll
  for (int off = 1; off < 64; off <<= 1) {
    uint32_t v = __shfl_up(pre, off);
    if (lane >= off) pre += v;
  }
  if (lane == 63) wtot[wv] = pre;
  __syncthreads();
  uint32_t wbase = 0;
  for (int w2 = 0; w2 < wv; w2++) wbase += wtot[w2];
  uint32_t excl = wbase + pre - s;
  if (t == 255) totE_s = excl + s;
  __syncthreads();
  // 3. gather entries (packed i<<16|j), row-major = ascending i
#pragma unroll
  for (int k = 0; k < 24; k++) {
    int r = t * 24 + k;
    for (uint32_t q = 0; q < cnt[k]; q++) {
      uint32_t dst = excl + loc[k] + q;
      if (dst < ELDS2)
        elds[dst] = ((uint32_t)r << 16) | (uint32_t)rows[(size_t)r * RCAP + q];
    }
  }
  __syncthreads();

  // 4. serial entry pass (wave 0, register-resident keep bitmap)
  if (t < 64) {
    int V = scal[4];
    if (V > (int)TOPK) V = (int)TOPK;
    unsigned long long k0, k1;
    { int d = V - lane * 64; k0 = (d <= 0) ? 0ull : ((d >= 64) ? ~0ull : ((1ull << d) - 1)); }
    { int d = V - (lane + 64) * 64;
      k1 = (lane + 64 < KW)
               ? ((d <= 0) ? 0ull : ((d >= 64) ? ~0ull : ((1ull << d) - 1)))
               : 0ull; }
    uint32_t E = totE_s;
    if (E > ELDS2) E = ELDS2;
    uint32_t cur = ((uint32_t)lane < E) ? elds[lane] : 0;
    for (uint32_t b0 = 0; b0 < E; b0 += 64) {
      uint32_t nxt = (b0 + 64 + (uint32_t)lane < E) ? elds[b0 + 64 + lane] : 0;
      uint32_t bn = E - b0; if (bn > 64) bn = 64;
      for (uint32_t idx = 0; idx < bn; idx++) {
        uint32_t e = __builtin_amdgcn_readlane(cur, idx);
        uint32_t i = e >> 16, j = e & 0xFFFFu;
        uint32_t wi = i >> 6;
        uint32_t lo, hi;
        if (wi < 64) {
          lo = __builtin_amdgcn_readlane((uint32_t)k0, wi);
          hi = __builtin_amdgcn_readlane((uint32_t)(k0 >> 32), wi);
        } else {
          lo = __builtin_amdgcn_readlane((uint32_t)k1, wi - 64);
          hi = __builtin_amdgcn_readlane((uint32_t)(k1 >> 32), wi - 64);
        }
        unsigned long long kw = ((unsigned long long)hi << 32) | lo;
        if ((kw >> (i & 63)) & 1ull) {
          uint32_t wj = j >> 6;
          unsigned long long bit = 1ull << (j & 63);
          if (wj < 64) { if ((uint32_t)lane == wj) k0 &= ~bit; }
          else         { if ((uint32_t)lane == wj - 64) k1 &= ~bit; }
        }
      }
      cur = nxt;
    }
    keep32[2 * lane] = (uint32_t)k0;
    keep32[2 * lane + 1] = (uint32_t)(k0 >> 32);
    if (lane + 64 < KW) {
      keep32[2 * (lane + 64)] = (uint32_t)k1;
      keep32[2 * (lane + 64) + 1] = (uint32_t)(k1 >> 32);
    }
  }
  __syncthreads();

  // 5. parallel rank of kept rows
  if (t < KW)
    wcnt_s[t] = (uint32_t)(__popc(keep32[2 * t]) + __popc(keep32[2 * t + 1]));
  __syncthreads();
  if (t < 64) {
    uint32_t v = wcnt_s[t], p2 = v;
#pragma unroll
    for (int off = 1; off < 64; off <<= 1) {
      uint32_t x = __shfl_up(p2, off);
      if (lane >= off) p2 += x;
    }
    wrank[t] = p2 - v;
    if (t == 63) carry_s = p2;
  }
  __syncthreads();
  if (t >= 64 && t < KW) {
    uint32_t v = wcnt_s[t], p2 = v;
#pragma unroll
    for (int off = 1; off < 64; off <<= 1) {
      uint32_t x = __shfl_up(p2, off);
      if (lane >= off) p2 += x;
    }
    wrank[t] = carry_s + p2 - v;
  }
  __syncthreads();
  for (int o = t; o < OUTK * 4; o += 256) out[o] = 0.0f;
  __syncthreads();
  for (int r = t; r < (int)TOPK; r += 256) {
    unsigned long long w =
        ((unsigned long long)keep32[2 * (r >> 6) + 1] << 32) | keep32[2 * (r >> 6)];
    int b = r & 63;
    if ((w >> b) & 1ull) {
      uint32_t rank = wrank[r >> 6] + (uint32_t)__popcll(w & ((1ull << b) - 1ull));
      if (rank < OUTK) {
        float4 bx = selbox[r];
        out[rank * 4 + 0] = bx.x;
        out[rank * 4 + 1] = bx.y;
        out[rank * 4 + 2] = bx.z;
        out[rank * 4 + 3] = bx.w;
      }
    }
  }
}

// ---------------- launch ----------------
extern "C" void kernel_launch(void* const* d_in, const int* in_sizes, int n_in,
                              void* d_out, int out_size, void* d_ws, size_t ws_size,
                              hipStream_t stream) {
  const float* cls    = (const float*)d_in[0];
  const float* reg    = (const float*)d_in[1];
  const float* anchor = (const float*)d_in[2];
  float* out = (float*)d_out;
  char* ws = (char*)d_ws;

  float4*   roi     = (float4*)(ws + OFF_ROI);
  uint32_t* key     = (uint32_t*)(ws + OFF_KEY);
  uint32_t* hist16  = (uint32_t*)(ws + OFF_HIST16);
  uint32_t* hists   = (uint32_t*)(ws + OFF_HISTS);
  uint32_t* hist8   = (uint32_t*)(ws + OFF_HIST8);
  int*      scal    = (int*)(ws + OFF_SCAL);
  uint32_t* rcnt    = (uint32_t*)(ws + OFF_RCNT);
  unsigned long long* sortbuf = (unsigned long long*)(ws + OFF_SORT);
  float4*   selbox  = (float4*)(ws + OFF_SELBOX);
  unsigned short* rows = (unsigned short*)(ws + OFF_ROWS);

  hipMemsetAsync(ws + OFF_HIST16, 0, ZERO_BYTES, stream);
  hipMemsetAsync(ws + OFF_SORT, 0xFF, (size_t)SORTN * 8, stream);

  int blocks = (NN + 255) / 256;
  k_decode<<<blocks, 256, 0, stream>>>(cls, reg, anchor, roi, key, hist16);
  k_hsum<<<65536 / 256, 256, 0, stream>>>(hist16, hists);
  k_scan16<<<1, 1024, 0, stream>>>(hists, scal);
  k_hist8<<<blocks, 256, 0, stream>>>(key, scal, hist8);
  k_scan8<<<1, 256, 0, stream>>>(hist8, scal);
  k_compact<<<blocks, 256, 0, stream>>>(key, scal, sortbuf);
  k_sortA<<<NCHUNK, 256, 0, stream>>>(sortbuf);
  k_sortB<<<SORTN / 256, 256, 0, stream>>>(sortbuf, roi, selbox);
  k_mask<<<dim3(KW, KW), 64, 0, stream>>>(selbox, rcnt, rows);
  k_seq<<<1, 256, 0, stream>>>(rcnt, rows, scal, selbox, out);
}

// Round 11
// 173.002 us; speedup vs baseline: 1.6332x; 1.6332x over previous
//
#include <hip/hip_runtime.h>
#include <stdint.h>

#pragma clang fp contract(off)

#define NN    300000
#define TOPK  6000u
#define KW    94
#define KPAD  6016
#define SORTN 8192
#define NCHUNK 16
#define CSZ   512
#define OUTK  300
#define RCAP  64
#define ELDS2 12288
#define NREP  8

// ---------------- workspace layout (bytes) ----------------
static constexpr size_t OFF_ROI    = 0;                                   // NN*16
static constexpr size_t OFF_KEY    = OFF_ROI + (size_t)NN * 16;           // NN*4
static constexpr size_t OFF_HIST16 = ((OFF_KEY + (size_t)NN * 4 + 255) & ~(size_t)255); // NREP*65536*4
static constexpr size_t OFF_HIST8  = OFF_HIST16 + (size_t)NREP * 65536 * 4; // 1 KB
static constexpr size_t OFF_SCAL   = OFF_HIST8 + 1024;                    // 256 B scalars
static constexpr size_t OFF_RCNT   = OFF_SCAL + 256;                      // KPAD*4 = 24064
static constexpr size_t ZERO_BYTES = (OFF_RCNT + (size_t)KPAD * 4) - OFF_HIST16;
static constexpr size_t OFF_HISTS  = OFF_RCNT + (size_t)KPAD * 4;         // 65536*4
static constexpr size_t OFF_SORT   = OFF_HISTS + 65536 * 4;               // SORTN*8
static constexpr size_t OFF_SELBOX = OFF_SORT + (size_t)SORTN * 8;        // KPAD*16
static constexpr size_t OFF_ROWS   = ((OFF_SELBOX + (size_t)KPAD * 16 + 255) & ~(size_t)255); // KPAD*RCAP*2

// scal[] layout: [0]=P16 bin, [1]=count_below16, [2]=T24 prefix, [3]=compact counter,
//                [4]=total valid count

__device__ __forceinline__ uint32_t score_key(float s) {
  uint32_t u = __float_as_uint(s);
  u = (u >> 31) ? ~u : (u | 0x80000000u);  // monotonic: ascending uint == ascending float
  return ~u;                               // invert: ascending uint == DESCENDING float
}

// bit-reversed histogram slot: consecutive bins -> distinct cache lines.
__device__ __forceinline__ uint32_t hslot(uint32_t b) { return __brev(b) >> 16; }

// ---------------- 1. decode + key + replicated 16-bit histogram ----------------
__global__ void k_decode(const float* __restrict__ cls, const float* __restrict__ reg,
                         const float* __restrict__ anchor, float4* __restrict__ roi,
                         uint32_t* __restrict__ key, uint32_t* __restrict__ hist16) {
  int i = blockIdx.x * blockDim.x + threadIdx.x;
  if (i >= NN) return;
  // softmax(cls)[1], bit-identical op sequence; exp(0)==1.0 exactly -> one f64 exp
  float c0 = cls[2 * i], c1 = cls[2 * i + 1];
  float m  = fmaxf(c0, c1);
  float a0 = c0 - m, a1 = c1 - m;          // one is exactly 0.0f
  float tn = fminf(a0, a1);
  float e  = (float)exp((double)tn);
  float e0 = (a0 == 0.0f) ? 1.0f : e;
  float e1 = (a1 == 0.0f) ? 1.0f : e;
  float s  = e1 / (e0 + e1);

  float4 a = ((const float4*)anchor)[i];
  float acx = (a.x + a.z) * 0.5f;
  float acy = (a.y + a.w) * 0.5f;
  float aw  = a.z - a.x;
  float ah  = a.w - a.y;
  float4 r = ((const float4*)reg)[i];
  float cx = r.x * aw + acx;
  float cy = r.y * ah + acy;
  float w  = (float)exp((double)r.z) * aw;
  float h  = (float)exp((double)r.w) * ah;
  float x1 = cx - w * 0.5f, y1 = cy - h * 0.5f;
  float x2 = cx + w * 0.5f, y2 = cy + h * 0.5f;
  x1 = fminf(fmaxf(x1, 0.0f), 1.0f);
  y1 = fminf(fmaxf(y1, 0.0f), 1.0f);
  x2 = fminf(fmaxf(x2, 0.0f), 1.0f);
  y2 = fminf(fmaxf(y2, 0.0f), 1.0f);
  float ws_ = x2 - x1, hs_ = y2 - y1;
  bool valid = (hs_ >= 0.001f) && (ws_ >= 0.001f);
  float msc = valid ? s : -__builtin_inff();
  uint32_t kk = score_key(msc);

  roi[i] = make_float4(x1, y1, x2, y2);
  key[i] = kk;
  // 8 histogram replicas (blockIdx&7): hottest line's serialized RMWs /8
  if (valid) atomicAdd(&hist16[((blockIdx.x & (NREP - 1)) << 16) + hslot(kk >> 16)], 1u);
}

// ---------------- 1b. reduce 8 replicas ----------------
__global__ void __launch_bounds__(256) k_hsum(const uint32_t* __restrict__ hist16,
                                              uint32_t* __restrict__ hists) {
  int i = blockIdx.x * 256 + threadIdx.x;  // 0..65535
  uint32_t s = 0;
#pragma unroll
  for (int r = 0; r < NREP; r++) s += hist16[(r << 16) + i];
  hists[i] = s;
}

// ---------------- 2. scan 65536-bin histogram (bit-reversed layout) ----------------
__global__ void __launch_bounds__(1024) k_scan16(const uint32_t* __restrict__ hists,
                                                 int* __restrict__ scal) {
  __shared__ unsigned short hh[65536];   // 128 KB
  __shared__ uint32_t part[1024];
  int t = threadIdx.x;
  const uint4* h4 = (const uint4*)hists;
#pragma unroll
  for (int k = 0; k < 16; k++) {
    uint4 v = h4[k * 1024 + t];
    uint32_t base = 4 * (k * 1024 + t);   // permuted-space index
    hh[__brev(base + 0) >> 16] = (unsigned short)v.x;  // brev is an involution
    hh[__brev(base + 1) >> 16] = (unsigned short)v.y;
    hh[__brev(base + 2) >> 16] = (unsigned short)v.z;
    hh[__brev(base + 3) >> 16] = (unsigned short)v.w;
  }
  __syncthreads();
  uint32_t sum = 0;
  for (int b = 0; b < 64; b++) sum += hh[t * 64 + b];
  part[t] = sum;
  __syncthreads();
  for (int off = 1; off < 1024; off <<= 1) {
    uint32_t v = (t >= off) ? part[t - off] : 0;
    __syncthreads();
    part[t] += v;
    __syncthreads();
  }
  if (t == 1023) scal[4] = (int)part[1023];   // total valid count
  uint32_t excl = part[t] - sum;
  if (excl < TOPK && excl + sum >= TOPK) {
    uint32_t cum = excl;
    for (int b = 0; b < 64; b++) {
      uint32_t h = hh[t * 64 + b];
      if (cum < TOPK && cum + h >= TOPK) { scal[0] = t * 64 + b; scal[1] = (int)cum; break; }
      cum += h;
    }
  }
}

// ---------------- 3. 8-bit refinement histogram ----------------
__global__ void k_hist8(const uint32_t* __restrict__ key, const int* __restrict__ scal,
                        uint32_t* __restrict__ hist8) {
  int i = blockIdx.x * blockDim.x + threadIdx.x;
  if (i >= NN) return;
  uint32_t P = (uint32_t)scal[0];
  uint32_t kk = key[i];
  if ((kk >> 16) == P) atomicAdd(&hist8[(kk >> 8) & 0xFFu], 1u);
}

__global__ void __launch_bounds__(256) k_scan8(const uint32_t* __restrict__ hist8,
                                               int* __restrict__ scal) {
  __shared__ uint32_t part[256];
  int t = threadIdx.x;
  uint32_t h = hist8[t];
  part[t] = h;
  __syncthreads();
  for (int off = 1; off < 256; off <<= 1) {
    uint32_t v = (t >= off) ? part[t - off] : 0;
    __syncthreads();
    part[t] += v;
    __syncthreads();
  }
  uint32_t excl = part[t] - h;
  uint32_t cb = (uint32_t)scal[1];
  if (cb + excl < TOPK && cb + excl + h >= TOPK)
    scal[2] = (scal[0] << 8) | t;
}

// ---------------- 4. compact candidates (prefix24 <= T24) ----------------
__global__ void k_compact(const uint32_t* __restrict__ key, int* __restrict__ scal,
                          unsigned long long* __restrict__ sortbuf) {
  __shared__ int lcnt, lbase;
  int t = threadIdx.x;
  int i = blockIdx.x * blockDim.x + t;
  if (t == 0) lcnt = 0;
  __syncthreads();
  bool sel = false;
  uint32_t kk = 0;
  int my = 0;
  if (i < NN) {
    uint32_t T24 = (uint32_t)scal[2];
    kk = key[i];
    if ((kk >> 8) <= T24) { sel = true; my = atomicAdd(&lcnt, 1); }
  }
  __syncthreads();
  if (t == 0 && lcnt > 0) lbase = atomicAdd(&scal[3], lcnt);
  __syncthreads();
  if (sel) {
    int pos = lbase + my;
    if (pos < SORTN) sortbuf[pos] = (((unsigned long long)kk) << 32) | (uint32_t)i;
  }
}

// ---------------- 5a. per-chunk bitonic sort (16 blocks x 512 elems, in place) --------
__global__ void __launch_bounds__(256) k_sortA(unsigned long long* __restrict__ sortbuf) {
  __shared__ unsigned long long sm[CSZ];
  int t = threadIdx.x;
  unsigned long long* chunk = sortbuf + (size_t)blockIdx.x * CSZ;
  sm[t] = chunk[t];
  sm[t + 256] = chunk[t + 256];
  __syncthreads();
  for (int k = 2; k <= CSZ; k <<= 1) {
    for (int j = k >> 1; j > 0; j >>= 1) {
      int i1 = ((t & ~(j - 1)) << 1) | (t & (j - 1));
      int i2 = i1 | j;
      bool up = ((i1 & k) == 0);
      unsigned long long a = sm[i1], b = sm[i2];
      if ((a > b) == up) { sm[i1] = b; sm[i2] = a; }
      __syncthreads();
    }
  }
  chunk[t] = sm[t];
  chunk[t + 256] = sm[t + 256];
}

// ---------------- 5b. stable multi-merge rank + scatter top-6000 ----------------
__global__ void __launch_bounds__(256) k_sortB(const unsigned long long* __restrict__ sortbuf,
                                               const float4* __restrict__ roi,
                                               float4* __restrict__ selbox) {
  int g = blockIdx.x * 256 + threadIdx.x;   // 0..8191
  int c = g >> 9, p = g & (CSZ - 1);
  unsigned long long val = sortbuf[g];
  int rank = p;
  for (int c2 = 0; c2 < NCHUNK; c2++) {
    if (c2 == c) continue;
    const unsigned long long* base = sortbuf + ((size_t)c2 << 9);
    bool le = (c2 < c);                     // earlier chunk: count <=, later: count <
    int pos = 0;
#pragma unroll
    for (int s = CSZ; s > 0; s >>= 1) {
      if (pos + s <= CSZ) {
        unsigned long long v = base[pos + s - 1];
        if (le ? (v <= val) : (v < val)) pos += s;
      }
    }
    rank += pos;
  }
  if (rank < (int)TOPK) {
    selbox[rank] = roi[(uint32_t)val];
  } else if (rank < KPAD) {
    selbox[rank] = make_float4(0.f, 0.f, 0.f, 0.f);
  }
}

// ---------------- 6. suppression pairs -> per-row lists ----------------
// rows[i][0..cnt): j's suppressed by i (j>i, IoU>0.7), intra- and inter-chunk.
__global__ void __launch_bounds__(64) k_mask(const float4* __restrict__ selbox,
                                             uint32_t* __restrict__ rcnt,
                                             unsigned short* __restrict__ rows) {
  int bi = blockIdx.x, bj = blockIdx.y;
  if (bj < bi) return;
  int t = threadIdx.x;
  __shared__ float4 jb[64];
  __shared__ float  ja[64];
  int j0 = bj * 64;
  float4 cb = selbox[j0 + t];
  jb[t] = cb;
  ja[t] = (cb.z - cb.x) * (cb.w - cb.y);
  __syncthreads();
  int i = bi * 64 + t;
  unsigned long long word = 0;
  if (i < (int)TOPK) {
    float4 bi4 = selbox[i];
    float ai = (bi4.z - bi4.x) * (bi4.w - bi4.y);
    for (int jj = 0; jj < 64; jj++) {
      int j = j0 + jj;
      float4 bb = jb[jj];
      float ltx = fmaxf(bi4.x, bb.x), lty = fmaxf(bi4.y, bb.y);
      float rbx = fminf(bi4.z, bb.z), rby = fminf(bi4.w, bb.w);
      float wx = fmaxf(rbx - ltx, 0.0f), wy = fmaxf(rby - lty, 0.0f);
      float inter = wx * wy;
      float iou = inter / (ai + ja[jj] - inter + 1e-9f);
      if (iou > 0.7f && j > i && j < (int)TOPK) word |= (1ull << jj);
    }
  }
  if (word) {
    uint32_t n = (uint32_t)__popcll(word);
    uint32_t pos = atomicAdd(&rcnt[i], n);
    unsigned long long rem = word;
    while (rem && pos < RCAP) {
      int jj = (int)__builtin_ctzll(rem);
      rem &= rem - 1;
      rows[(size_t)i * RCAP + pos] = (unsigned short)(j0 + jj);
      pos++;
    }
  }
}

// ---------------- 7. greedy keep via PARALLEL FIXPOINT iteration ----------------
// Greedy NMS keep is the unique fixpoint of keep[j] = valid[j] && !any edge
// (i,j) with keep[i] (edges strictly forward => unique; converges in
// DAG-depth+1 iterations). Each iteration is fully parallel over E entries
// (LDS atomicOr into a suppress bitmap), double-buffered keep, change-flag
// terminated. E ~ 3.6K, depth ~ O(log n) => a few microseconds.
__global__ void __launch_bounds__(256) k_seq(const uint32_t* __restrict__ rcnt,
                                             const unsigned short* __restrict__ rows,
                                             const int* __restrict__ scal,
                                             const float4* __restrict__ selbox,
                                             float* __restrict__ out) {
  __shared__ uint32_t elds[ELDS2];            // 48 KB packed entries (i<<16|j)
  __shared__ uint32_t ecur;
  __shared__ uint32_t valid32[2 * KW], keepA[2 * KW], keepB[2 * KW], sup32[2 * KW];
  __shared__ uint32_t wcnt_s[KW], wrank[KW];
  __shared__ int chg;
  __shared__ uint32_t carry_s;
  const int t = threadIdx.x, lane = t & 63;

  // gather entries (order irrelevant for fixpoint): LDS cursor, one atomicAdd
  // per non-empty row; rcnt reads coalesced (stride-256).
  if (t == 0) ecur = 0;
  {
    int V = scal[4];
    if (V > (int)TOPK) V = (int)TOPK;
    if (t < 2 * KW) {
      int d = V - t * 32;
      uint32_t v = (d <= 0) ? 0u : ((d >= 32) ? 0xFFFFFFFFu : ((1u << d) - 1u));
      valid32[t] = v;
      keepA[t] = v;
    }
  }
  __syncthreads();
  for (int r = t; r < KPAD; r += 256) {
    uint32_t c = rcnt[r];
    c = (c > RCAP) ? RCAP : c;
    if (c) {
      uint32_t base = atomicAdd(&ecur, c);
      for (uint32_t q = 0; q < c; q++) {
        uint32_t dst = base + q;
        if (dst < ELDS2)
          elds[dst] = ((uint32_t)r << 16) | (uint32_t)rows[(size_t)r * RCAP + q];
      }
    }
  }
  __syncthreads();
  uint32_t E = ecur;
  if (E > ELDS2) E = ELDS2;

  // fixpoint iteration
  for (;;) {
    if (t < 2 * KW) sup32[t] = 0;
    if (t == 0) chg = 0;
    __syncthreads();
    for (uint32_t k = t; k < E; k += 256) {
      uint32_t e = elds[k];
      uint32_t i = e >> 16, j = e & 0xFFFFu;
      if ((keepA[i >> 5] >> (i & 31)) & 1u)
        atomicOr(&sup32[j >> 5], 1u << (j & 31));
    }
    __syncthreads();
    if (t < 2 * KW) {
      uint32_t nw = valid32[t] & ~sup32[t];
      if (nw != keepA[t]) chg = 1;      // benign same-value race
      keepB[t] = nw;
    }
    __syncthreads();
    if (!chg) break;                    // keepA already == fixpoint
    if (t < 2 * KW) keepA[t] = keepB[t];
    __syncthreads();
  }

  // parallel rank of kept rows
  if (t < KW)
    wcnt_s[t] = (uint32_t)(__popc(keepA[2 * t]) + __popc(keepA[2 * t + 1]));
  __syncthreads();
  if (t < 64) {
    uint32_t v = wcnt_s[t], p2 = v;
#pragma unroll
    for (int off = 1; off < 64; off <<= 1) {
      uint32_t x = __shfl_up(p2, off);
      if (lane >= off) p2 += x;
    }
    wrank[t] = p2 - v;
    if (t == 63) carry_s = p2;
  }
  __syncthreads();
  if (t >= 64 && t < KW) {
    uint32_t v = wcnt_s[t], p2 = v;
#pragma unroll
    for (int off = 1; off < 64; off <<= 1) {
      uint32_t x = __shfl_up(p2, off);
      if (lane >= off) p2 += x;
    }
    wrank[t] = carry_s + p2 - v;
  }
  __syncthreads();
  for (int o = t; o < OUTK * 4; o += 256) out[o] = 0.0f;
  __syncthreads();
  for (int r = t; r < (int)TOPK; r += 256) {
    unsigned long long w =
        ((unsigned long long)keepA[2 * (r >> 6) + 1] << 32) | keepA[2 * (r >> 6)];
    int b = r & 63;
    if ((w >> b) & 1ull) {
      uint32_t rank = wrank[r >> 6] + (uint32_t)__popcll(w & ((1ull << b) - 1ull));
      if (rank < OUTK) {
        float4 bx = selbox[r];
        out[rank * 4 + 0] = bx.x;
        out[rank * 4 + 1] = bx.y;
        out[rank * 4 + 2] = bx.z;
        out[rank * 4 + 3] = bx.w;
      }
    }
  }
}

// ---------------- launch ----------------
extern "C" void kernel_launch(void* const* d_in, const int* in_sizes, int n_in,
                              void* d_out, int out_size, void* d_ws, size_t ws_size,
                              hipStream_t stream) {
  const float* cls    = (const float*)d_in[0];
  const float* reg    = (const float*)d_in[1];
  const float* anchor = (const float*)d_in[2];
  float* out = (float*)d_out;
  char* ws = (char*)d_ws;

  float4*   roi     = (float4*)(ws + OFF_ROI);
  uint32_t* key     = (uint32_t*)(ws + OFF_KEY);
  uint32_t* hist16  = (uint32_t*)(ws + OFF_HIST16);
  uint32_t* hists   = (uint32_t*)(ws + OFF_HISTS);
  uint32_t* hist8   = (uint32_t*)(ws + OFF_HIST8);
  int*      scal    = (int*)(ws + OFF_SCAL);
  uint32_t* rcnt    = (uint32_t*)(ws + OFF_RCNT);
  unsigned long long* sortbuf = (unsigned long long*)(ws + OFF_SORT);
  float4*   selbox  = (float4*)(ws + OFF_SELBOX);
  unsigned short* rows = (unsigned short*)(ws + OFF_ROWS);

  hipMemsetAsync(ws + OFF_HIST16, 0, ZERO_BYTES, stream);
  hipMemsetAsync(ws + OFF_SORT, 0xFF, (size_t)SORTN * 8, stream);

  int blocks = (NN + 255) / 256;
  k_decode<<<blocks, 256, 0, stream>>>(cls, reg, anchor, roi, key, hist16);
  k_hsum<<<65536 / 256, 256, 0, stream>>>(hist16, hists);
  k_scan16<<<1, 1024, 0, stream>>>(hists, scal);
  k_hist8<<<blocks, 256, 0, stream>>>(key, scal, hist8);
  k_scan8<<<1, 256, 0, stream>>>(hist8, scal);
  k_compact<<<blocks, 256, 0, stream>>>(key, scal, sortbuf);
  k_sortA<<<NCHUNK, 256, 0, stream>>>(sortbuf);
  k_sortB<<<SORTN / 256, 256, 0, stream>>>(sortbuf, roi, selbox);
  k_mask<<<dim3(KW, KW), 64, 0, stream>>>(selbox, rcnt, rows);
  k_seq<<<1, 256, 0, stream>>>(rcnt, rows, scal, selbox, out);
}

// Round 12
// 171.028 us; speedup vs baseline: 1.6520x; 1.0115x over previous
//
#include <hip/hip_runtime.h>
#include <stdint.h>

#pragma clang fp contract(off)

#define NN    300000
#define TOPK  6000u
#define KW    94
#define KPAD  6016
#define SORTN 8192
#define NCHUNK 16
#define CSZ   512
#define OUTK  300
#define RCAP  64
#define ELDS2 12288
#define NREP  8

// ---------------- workspace layout (bytes) ----------------
static constexpr size_t OFF_ROI    = 0;                                   // NN*16
static constexpr size_t OFF_KEY    = OFF_ROI + (size_t)NN * 16;           // NN*4
static constexpr size_t OFF_HIST16 = ((OFF_KEY + (size_t)NN * 4 + 255) & ~(size_t)255); // NREP*65536*4
static constexpr size_t OFF_HIST8  = OFF_HIST16 + (size_t)NREP * 65536 * 4; // 1 KB
static constexpr size_t OFF_SCAL   = OFF_HIST8 + 1024;                    // 256 B scalars
static constexpr size_t OFF_RCNT   = OFF_SCAL + 256;                      // KPAD*4 = 24064
static constexpr size_t ZERO_BYTES = (OFF_RCNT + (size_t)KPAD * 4) - OFF_HIST16;
static constexpr size_t OFF_HISTS  = OFF_RCNT + (size_t)KPAD * 4;         // 65536*4
static constexpr size_t OFF_SORT   = OFF_HISTS + 65536 * 4;               // SORTN*8
static constexpr size_t OFF_SELBOX = OFF_SORT + (size_t)SORTN * 8;        // KPAD*16
static constexpr size_t OFF_ROWS   = ((OFF_SELBOX + (size_t)KPAD * 16 + 255) & ~(size_t)255); // KPAD*RCAP*2

// scal[] layout: [0]=P16 bin, [1]=count_below16, [2]=T24 prefix, [3]=compact counter,
//                [4]=total valid count

static constexpr uint32_t ZG = (uint32_t)(ZERO_BYTES / 16);   // 16B granules to zero
static constexpr uint32_t SG = (uint32_t)(SORTN * 8 / 16);    // 16B granules of 0xFF
static constexpr uint32_t INIT_BLOCKS = (ZG + SG + 255) / 256;

__device__ __forceinline__ uint32_t score_key(float s) {
  uint32_t u = __float_as_uint(s);
  u = (u >> 31) ? ~u : (u | 0x80000000u);  // monotonic: ascending uint == ascending float
  return ~u;                               // invert: ascending uint == DESCENDING float
}

// bit-reversed histogram slot: consecutive bins -> distinct cache lines.
__device__ __forceinline__ uint32_t hslot(uint32_t b) { return __brev(b) >> 16; }

// ---------------- 0. workspace init (replaces runtime fillBuffer: was 2x40us) --------
__global__ void __launch_bounds__(256) k_init(char* __restrict__ ws) {
  uint32_t idx = blockIdx.x * 256 + threadIdx.x;
  if (idx < ZG) {
    ((uint4*)(ws + OFF_HIST16))[idx] = make_uint4(0u, 0u, 0u, 0u);
  } else if (idx < ZG + SG) {
    ((uint4*)(ws + OFF_SORT))[idx - ZG] = make_uint4(~0u, ~0u, ~0u, ~0u);
  }
}

// ---------------- 1. decode + key + replicated 16-bit histogram ----------------
__global__ void k_decode(const float* __restrict__ cls, const float* __restrict__ reg,
                         const float* __restrict__ anchor, float4* __restrict__ roi,
                         uint32_t* __restrict__ key, uint32_t* __restrict__ hist16) {
  int i = blockIdx.x * blockDim.x + threadIdx.x;
  if (i >= NN) return;
  // softmax(cls)[1], bit-identical op sequence; exp(0)==1.0 exactly -> one f64 exp
  float c0 = cls[2 * i], c1 = cls[2 * i + 1];
  float m  = fmaxf(c0, c1);
  float a0 = c0 - m, a1 = c1 - m;          // one is exactly 0.0f
  float tn = fminf(a0, a1);
  float e  = (float)exp((double)tn);
  float e0 = (a0 == 0.0f) ? 1.0f : e;
  float e1 = (a1 == 0.0f) ? 1.0f : e;
  float s  = e1 / (e0 + e1);

  float4 a = ((const float4*)anchor)[i];
  float acx = (a.x + a.z) * 0.5f;
  float acy = (a.y + a.w) * 0.5f;
  float aw  = a.z - a.x;
  float ah  = a.w - a.y;
  float4 r = ((const float4*)reg)[i];
  float cx = r.x * aw + acx;
  float cy = r.y * ah + acy;
  float w  = (float)exp((double)r.z) * aw;
  float h  = (float)exp((double)r.w) * ah;
  float x1 = cx - w * 0.5f, y1 = cy - h * 0.5f;
  float x2 = cx + w * 0.5f, y2 = cy + h * 0.5f;
  x1 = fminf(fmaxf(x1, 0.0f), 1.0f);
  y1 = fminf(fmaxf(y1, 0.0f), 1.0f);
  x2 = fminf(fmaxf(x2, 0.0f), 1.0f);
  y2 = fminf(fmaxf(y2, 0.0f), 1.0f);
  float ws_ = x2 - x1, hs_ = y2 - y1;
  bool valid = (hs_ >= 0.001f) && (ws_ >= 0.001f);
  float msc = valid ? s : -__builtin_inff();
  uint32_t kk = score_key(msc);

  roi[i] = make_float4(x1, y1, x2, y2);
  key[i] = kk;
  // 8 histogram replicas (blockIdx&7): hottest line's serialized RMWs /8
  if (valid) atomicAdd(&hist16[((blockIdx.x & (NREP - 1)) << 16) + hslot(kk >> 16)], 1u);
}

// ---------------- 1b. reduce 8 replicas ----------------
__global__ void __launch_bounds__(256) k_hsum(const uint32_t* __restrict__ hist16,
                                              uint32_t* __restrict__ hists) {
  int i = blockIdx.x * 256 + threadIdx.x;  // 0..65535
  uint32_t s = 0;
#pragma unroll
  for (int r = 0; r < NREP; r++) s += hist16[(r << 16) + i];
  hists[i] = s;
}

// ---------------- 2. scan 65536-bin histogram (bit-reversed layout) ----------------
__global__ void __launch_bounds__(1024) k_scan16(const uint32_t* __restrict__ hists,
                                                 int* __restrict__ scal) {
  __shared__ unsigned short hh[65536];   // 128 KB
  __shared__ uint32_t part[1024];
  int t = threadIdx.x;
  const uint4* h4 = (const uint4*)hists;
#pragma unroll
  for (int k = 0; k < 16; k++) {
    uint4 v = h4[k * 1024 + t];
    uint32_t base = 4 * (k * 1024 + t);   // permuted-space index
    hh[__brev(base + 0) >> 16] = (unsigned short)v.x;  // brev is an involution
    hh[__brev(base + 1) >> 16] = (unsigned short)v.y;
    hh[__brev(base + 2) >> 16] = (unsigned short)v.z;
    hh[__brev(base + 3) >> 16] = (unsigned short)v.w;
  }
  __syncthreads();
  uint32_t sum = 0;
  for (int b = 0; b < 64; b++) sum += hh[t * 64 + b];
  part[t] = sum;
  __syncthreads();
  for (int off = 1; off < 1024; off <<= 1) {
    uint32_t v = (t >= off) ? part[t - off] : 0;
    __syncthreads();
    part[t] += v;
    __syncthreads();
  }
  if (t == 1023) scal[4] = (int)part[1023];   // total valid count
  uint32_t excl = part[t] - sum;
  if (excl < TOPK && excl + sum >= TOPK) {
    uint32_t cum = excl;
    for (int b = 0; b < 64; b++) {
      uint32_t h = hh[t * 64 + b];
      if (cum < TOPK && cum + h >= TOPK) { scal[0] = t * 64 + b; scal[1] = (int)cum; break; }
      cum += h;
    }
  }
}

// ---------------- 3. 8-bit refinement histogram ----------------
__global__ void k_hist8(const uint32_t* __restrict__ key, const int* __restrict__ scal,
                        uint32_t* __restrict__ hist8) {
  int i = blockIdx.x * blockDim.x + threadIdx.x;
  if (i >= NN) return;
  uint32_t P = (uint32_t)scal[0];
  uint32_t kk = key[i];
  if ((kk >> 16) == P) atomicAdd(&hist8[(kk >> 8) & 0xFFu], 1u);
}

__global__ void __launch_bounds__(256) k_scan8(const uint32_t* __restrict__ hist8,
                                               int* __restrict__ scal) {
  __shared__ uint32_t part[256];
  int t = threadIdx.x;
  uint32_t h = hist8[t];
  part[t] = h;
  __syncthreads();
  for (int off = 1; off < 256; off <<= 1) {
    uint32_t v = (t >= off) ? part[t - off] : 0;
    __syncthreads();
    part[t] += v;
    __syncthreads();
  }
  uint32_t excl = part[t] - h;
  uint32_t cb = (uint32_t)scal[1];
  if (cb + excl < TOPK && cb + excl + h >= TOPK)
    scal[2] = (scal[0] << 8) | t;
}

// ---------------- 4. compact candidates (prefix24 <= T24) ----------------
__global__ void k_compact(const uint32_t* __restrict__ key, int* __restrict__ scal,
                          unsigned long long* __restrict__ sortbuf) {
  __shared__ int lcnt, lbase;
  int t = threadIdx.x;
  int i = blockIdx.x * blockDim.x + t;
  if (t == 0) lcnt = 0;
  __syncthreads();
  bool sel = false;
  uint32_t kk = 0;
  int my = 0;
  if (i < NN) {
    uint32_t T24 = (uint32_t)scal[2];
    kk = key[i];
    if ((kk >> 8) <= T24) { sel = true; my = atomicAdd(&lcnt, 1); }
  }
  __syncthreads();
  if (t == 0 && lcnt > 0) lbase = atomicAdd(&scal[3], lcnt);
  __syncthreads();
  if (sel) {
    int pos = lbase + my;
    if (pos < SORTN) sortbuf[pos] = (((unsigned long long)kk) << 32) | (uint32_t)i;
  }
}

// ---------------- 5a. per-chunk bitonic sort (16 blocks x 512 elems, in place) --------
__global__ void __launch_bounds__(256) k_sortA(unsigned long long* __restrict__ sortbuf) {
  __shared__ unsigned long long sm[CSZ];
  int t = threadIdx.x;
  unsigned long long* chunk = sortbuf + (size_t)blockIdx.x * CSZ;
  sm[t] = chunk[t];
  sm[t + 256] = chunk[t + 256];
  __syncthreads();
  for (int k = 2; k <= CSZ; k <<= 1) {
    for (int j = k >> 1; j > 0; j >>= 1) {
      int i1 = ((t & ~(j - 1)) << 1) | (t & (j - 1));
      int i2 = i1 | j;
      bool up = ((i1 & k) == 0);
      unsigned long long a = sm[i1], b = sm[i2];
      if ((a > b) == up) { sm[i1] = b; sm[i2] = a; }
      __syncthreads();
    }
  }
  chunk[t] = sm[t];
  chunk[t + 256] = sm[t + 256];
}

// ---------------- 5b. stable multi-merge rank + scatter top-6000 ----------------
__global__ void __launch_bounds__(256) k_sortB(const unsigned long long* __restrict__ sortbuf,
                                               const float4* __restrict__ roi,
                                               float4* __restrict__ selbox) {
  int g = blockIdx.x * 256 + threadIdx.x;   // 0..8191
  int c = g >> 9, p = g & (CSZ - 1);
  unsigned long long val = sortbuf[g];
  int rank = p;
  for (int c2 = 0; c2 < NCHUNK; c2++) {
    if (c2 == c) continue;
    const unsigned long long* base = sortbuf + ((size_t)c2 << 9);
    bool le = (c2 < c);                     // earlier chunk: count <=, later: count <
    int pos = 0;
#pragma unroll
    for (int s = CSZ; s > 0; s >>= 1) {
      if (pos + s <= CSZ) {
        unsigned long long v = base[pos + s - 1];
        if (le ? (v <= val) : (v < val)) pos += s;
      }
    }
    rank += pos;
  }
  if (rank < (int)TOPK) {
    selbox[rank] = roi[(uint32_t)val];
  } else if (rank < KPAD) {
    selbox[rank] = make_float4(0.f, 0.f, 0.f, 0.f);
  }
}

// ---------------- 6. suppression pairs -> per-row lists ----------------
// rows[i][0..cnt): j's suppressed by i (j>i, IoU>0.7), intra- and inter-chunk.
__global__ void __launch_bounds__(64) k_mask(const float4* __restrict__ selbox,
                                             uint32_t* __restrict__ rcnt,
                                             unsigned short* __restrict__ rows) {
  int bi = blockIdx.x, bj = blockIdx.y;
  if (bj < bi) return;
  int t = threadIdx.x;
  __shared__ float4 jb[64];
  __shared__ float  ja[64];
  int j0 = bj * 64;
  float4 cb = selbox[j0 + t];
  jb[t] = cb;
  ja[t] = (cb.z - cb.x) * (cb.w - cb.y);
  __syncthreads();
  int i = bi * 64 + t;
  unsigned long long word = 0;
  if (i < (int)TOPK) {
    float4 bi4 = selbox[i];
    float ai = (bi4.z - bi4.x) * (bi4.w - bi4.y);
    for (int jj = 0; jj < 64; jj++) {
      int j = j0 + jj;
      float4 bb = jb[jj];
      float ltx = fmaxf(bi4.x, bb.x), lty = fmaxf(bi4.y, bb.y);
      float rbx = fminf(bi4.z, bb.z), rby = fminf(bi4.w, bb.w);
      float wx = fmaxf(rbx - ltx, 0.0f), wy = fmaxf(rby - lty, 0.0f);
      float inter = wx * wy;
      float iou = inter / (ai + ja[jj] - inter + 1e-9f);
      if (iou > 0.7f && j > i && j < (int)TOPK) word |= (1ull << jj);
    }
  }
  if (word) {
    uint32_t n = (uint32_t)__popcll(word);
    uint32_t pos = atomicAdd(&rcnt[i], n);
    unsigned long long rem = word;
    while (rem && pos < RCAP) {
      int jj = (int)__builtin_ctzll(rem);
      rem &= rem - 1;
      rows[(size_t)i * RCAP + pos] = (unsigned short)(j0 + jj);
      pos++;
    }
  }
}

// ---------------- 7. greedy keep via PARALLEL FIXPOINT iteration ----------------
// keep = unique fixpoint of keep[j] = valid[j] && !any edge (i,j) with keep[i]
// (forward edges => unique; converges in DAG-depth+1 Jacobi sweeps).
// Gather: wave-aggregated LDS cursor (1 atomic/wave/tile, not 1 per row).
// Fixpoint: ping-pong keep buffers (no copy phase), 3 barriers/sweep.
__global__ void __launch_bounds__(256) k_seq(const uint32_t* __restrict__ rcnt,
                                             const unsigned short* __restrict__ rows,
                                             const int* __restrict__ scal,
                                             const float4* __restrict__ selbox,
                                             float* __restrict__ out) {
  __shared__ uint32_t elds[ELDS2];            // 48 KB packed entries (i<<16|j)
  __shared__ uint32_t ecur;
  __shared__ uint32_t valid32[2 * KW], keepP[2][2 * KW], sup32[2 * KW];
  __shared__ uint32_t wcnt_s[KW], wrank[KW];
  __shared__ int chg;
  __shared__ uint32_t carry_s;
  const int t = threadIdx.x, lane = t & 63;

  if (t == 0) ecur = 0;
  {
    int V = scal[4];
    if (V > (int)TOPK) V = (int)TOPK;
    if (t < 2 * KW) {
      int d = V - t * 32;
      uint32_t v = (d <= 0) ? 0u : ((d >= 32) ? 0xFFFFFFFFu : ((1u << d) - 1u));
      valid32[t] = v;
      keepP[0][t] = v;
    }
  }
  __syncthreads();
  // gather entries: per-256-row tile, wave prefix of counts + 1 atomic per wave
  for (int rr = 0; rr < KPAD; rr += 256) {
    int r = rr + t;
    uint32_t c = 0;
    if (r < KPAD) { c = rcnt[r]; c = (c > RCAP) ? RCAP : c; }
    uint32_t pre = c;
#pragma unroll
    for (int off = 1; off < 64; off <<= 1) {
      uint32_t v = __shfl_up(pre, off);
      if (lane >= off) pre += v;
    }
    uint32_t wt = __shfl(pre, 63);
    uint32_t bb = 0;
    if (wt) {
      if (lane == 63) bb = atomicAdd(&ecur, wt);
      bb = __shfl(bb, 63);
    }
    uint32_t dst0 = bb + pre - c;
    for (uint32_t q = 0; q < c; q++) {
      uint32_t dst = dst0 + q;
      if (dst < ELDS2)
        elds[dst] = ((uint32_t)r << 16) | (uint32_t)rows[(size_t)r * RCAP + q];
    }
  }
  __syncthreads();
  uint32_t E = ecur;
  if (E > ELDS2) E = ELDS2;

  // Jacobi fixpoint, ping-pong buffers
  int p = 0;
  for (;;) {
    if (t < 2 * KW) sup32[t] = 0;
    if (t == 0) chg = 0;
    __syncthreads();
    for (uint32_t k = t; k < E; k += 256) {
      uint32_t e = elds[k];
      uint32_t i = e >> 16, j = e & 0xFFFFu;
      if ((keepP[p][i >> 5] >> (i & 31)) & 1u)
        atomicOr(&sup32[j >> 5], 1u << (j & 31));
    }
    __syncthreads();
    if (t < 2 * KW) {
      uint32_t nw = valid32[t] & ~sup32[t];
      keepP[p ^ 1][t] = nw;
      if (nw != keepP[p][t]) chg = 1;   // benign same-value race
    }
    __syncthreads();
    p ^= 1;
    if (!chg) break;                    // converged: keepP[p] == keepP[p^1]
  }

  // parallel rank of kept rows
  if (t < KW)
    wcnt_s[t] = (uint32_t)(__popc(keepP[p][2 * t]) + __popc(keepP[p][2 * t + 1]));
  __syncthreads();
  if (t < 64) {
    uint32_t v = wcnt_s[t], p2 = v;
#pragma unroll
    for (int off = 1; off < 64; off <<= 1) {
      uint32_t x = __shfl_up(p2, off);
      if (lane >= off) p2 += x;
    }
    wrank[t] = p2 - v;
    if (t == 63) carry_s = p2;
  }
  __syncthreads();
  if (t >= 64 && t < KW) {
    uint32_t v = wcnt_s[t], p2 = v;
#pragma unroll
    for (int off = 1; off < 64; off <<= 1) {
      uint32_t x = __shfl_up(p2, off);
      if (lane >= off) p2 += x;
    }
    wrank[t] = carry_s + p2 - v;
  }
  __syncthreads();
  for (int o = t; o < OUTK * 4; o += 256) out[o] = 0.0f;
  __syncthreads();
  for (int r = t; r < (int)TOPK; r += 256) {
    unsigned long long w =
        ((unsigned long long)keepP[p][2 * (r >> 6) + 1] << 32) | keepP[p][2 * (r >> 6)];
    int b = r & 63;
    if ((w >> b) & 1ull) {
      uint32_t rank = wrank[r >> 6] + (uint32_t)__popcll(w & ((1ull << b) - 1ull));
      if (rank < OUTK) {
        float4 bx = selbox[r];
        out[rank * 4 + 0] = bx.x;
        out[rank * 4 + 1] = bx.y;
        out[rank * 4 + 2] = bx.z;
        out[rank * 4 + 3] = bx.w;
      }
    }
  }
}

// ---------------- launch ----------------
extern "C" void kernel_launch(void* const* d_in, const int* in_sizes, int n_in,
                              void* d_out, int out_size, void* d_ws, size_t ws_size,
                              hipStream_t stream) {
  const float* cls    = (const float*)d_in[0];
  const float* reg    = (const float*)d_in[1];
  const float* anchor = (const float*)d_in[2];
  float* out = (float*)d_out;
  char* ws = (char*)d_ws;

  float4*   roi     = (float4*)(ws + OFF_ROI);
  uint32_t* key     = (uint32_t*)(ws + OFF_KEY);
  uint32_t* hist16  = (uint32_t*)(ws + OFF_HIST16);
  uint32_t* hists   = (uint32_t*)(ws + OFF_HISTS);
  uint32_t* hist8   = (uint32_t*)(ws + OFF_HIST8);
  int*      scal    = (int*)(ws + OFF_SCAL);
  uint32_t* rcnt    = (uint32_t*)(ws + OFF_RCNT);
  unsigned long long* sortbuf = (unsigned long long*)(ws + OFF_SORT);
  float4*   selbox  = (float4*)(ws + OFF_SELBOX);
  unsigned short* rows = (unsigned short*)(ws + OFF_ROWS);

  int blocks = (NN + 255) / 256;
  k_init<<<INIT_BLOCKS, 256, 0, stream>>>(ws);
  k_decode<<<blocks, 256, 0, stream>>>(cls, reg, anchor, roi, key, hist16);
  k_hsum<<<65536 / 256, 256, 0, stream>>>(hist16, hists);
  k_scan16<<<1, 1024, 0, stream>>>(hists, scal);
  k_hist8<<<blocks, 256, 0, stream>>>(key, scal, hist8);
  k_scan8<<<1, 256, 0, stream>>>(hist8, scal);
  k_compact<<<blocks, 256, 0, stream>>>(key, scal, sortbuf);
  k_sortA<<<NCHUNK, 256, 0, stream>>>(sortbuf);
  k_sortB<<<SORTN / 256, 256, 0, stream>>>(sortbuf, roi, selbox);
  k_mask<<<dim3(KW, KW), 64, 0, stream>>>(selbox, rcnt, rows);
  k_seq<<<1, 256, 0, stream>>>(rcnt, rows, scal, selbox, out);
}

// Round 13
// 163.453 us; speedup vs baseline: 1.7286x; 1.0463x over previous
//
#include <hip/hip_runtime.h>
#include <stdint.h>

#pragma clang fp contract(off)

#define NN    300000
#define TOPK  6000u
#define KW    94
#define KPAD  6016
#define SORTN 8192
#define NCHUNK 16
#define CSZ   512
#define OUTK  300
#define RCAP  64
#define ELDS2 12288
#define NREP  8

// ---------------- workspace layout (bytes) ----------------
static constexpr size_t OFF_ROI    = 0;                                   // NN*16
static constexpr size_t OFF_KEY    = OFF_ROI + (size_t)NN * 16;           // NN*4
static constexpr size_t OFF_HIST16 = ((OFF_KEY + (size_t)NN * 4 + 255) & ~(size_t)255); // NREP*65536*4
static constexpr size_t OFF_HIST8  = OFF_HIST16 + (size_t)NREP * 65536 * 4; // 1 KB
static constexpr size_t OFF_SCAL   = OFF_HIST8 + 1024;                    // 256 B scalars
static constexpr size_t OFF_RCNT   = OFF_SCAL + 256;                      // KPAD*4
static constexpr size_t ZERO_BYTES = (OFF_RCNT + (size_t)KPAD * 4) - OFF_HIST16;
static constexpr size_t OFF_HISTS  = OFF_RCNT + (size_t)KPAD * 4;         // 65536*4
static constexpr size_t OFF_SORT   = OFF_HISTS + 65536 * 4;               // SORTN*8
static constexpr size_t OFF_SELBOX = OFF_SORT + (size_t)SORTN * 8;        // KPAD*16
static constexpr size_t OFF_DIAG   = ((OFF_SELBOX + (size_t)KPAD * 16 + 255) & ~(size_t)255); // KPAD*8
static constexpr size_t OFF_ROWS   = OFF_DIAG + (size_t)KPAD * 8;         // KPAD*RCAP*2

// scal[]: [0]=P16 bin, [1]=count_below16, [2]=T24 prefix, [3]=compact counter, [4]=valid total

static constexpr uint32_t ZG = (uint32_t)(ZERO_BYTES / 16);
static constexpr uint32_t SG = (uint32_t)(SORTN * 8 / 16);
static constexpr uint32_t INIT_BLOCKS = (ZG + SG + 255) / 256;

__device__ __forceinline__ uint32_t score_key(float s) {
  uint32_t u = __float_as_uint(s);
  u = (u >> 31) ? ~u : (u | 0x80000000u);
  return ~u;
}
__device__ __forceinline__ uint32_t hslot(uint32_t b) { return __brev(b) >> 16; }

// ---------------- 0. workspace init ----------------
__global__ void __launch_bounds__(256) k_init(char* __restrict__ ws) {
  uint32_t idx = blockIdx.x * 256 + threadIdx.x;
  if (idx < ZG) {
    ((uint4*)(ws + OFF_HIST16))[idx] = make_uint4(0u, 0u, 0u, 0u);
  } else if (idx < ZG + SG) {
    ((uint4*)(ws + OFF_SORT))[idx - ZG] = make_uint4(~0u, ~0u, ~0u, ~0u);
  }
}

// ---------------- 1. decode + key + replicated 16-bit histogram ----------------
__global__ void k_decode(const float* __restrict__ cls, const float* __restrict__ reg,
                         const float* __restrict__ anchor, float4* __restrict__ roi,
                         uint32_t* __restrict__ key, uint32_t* __restrict__ hist16) {
  int i = blockIdx.x * blockDim.x + threadIdx.x;
  if (i >= NN) return;
  float c0 = cls[2 * i], c1 = cls[2 * i + 1];
  float m  = fmaxf(c0, c1);
  float a0 = c0 - m, a1 = c1 - m;
  float tn = fminf(a0, a1);
  float e  = (float)exp((double)tn);
  float e0 = (a0 == 0.0f) ? 1.0f : e;
  float e1 = (a1 == 0.0f) ? 1.0f : e;
  float s  = e1 / (e0 + e1);

  float4 a = ((const float4*)anchor)[i];
  float acx = (a.x + a.z) * 0.5f;
  float acy = (a.y + a.w) * 0.5f;
  float aw  = a.z - a.x;
  float ah  = a.w - a.y;
  float4 r = ((const float4*)reg)[i];
  float cx = r.x * aw + acx;
  float cy = r.y * ah + acy;
  float w  = (float)exp((double)r.z) * aw;
  float h  = (float)exp((double)r.w) * ah;
  float x1 = cx - w * 0.5f, y1 = cy - h * 0.5f;
  float x2 = cx + w * 0.5f, y2 = cy + h * 0.5f;
  x1 = fminf(fmaxf(x1, 0.0f), 1.0f);
  y1 = fminf(fmaxf(y1, 0.0f), 1.0f);
  x2 = fminf(fmaxf(x2, 0.0f), 1.0f);
  y2 = fminf(fmaxf(y2, 0.0f), 1.0f);
  float ws_ = x2 - x1, hs_ = y2 - y1;
  bool valid = (hs_ >= 0.001f) && (ws_ >= 0.001f);
  float msc = valid ? s : -__builtin_inff();
  uint32_t kk = score_key(msc);

  roi[i] = make_float4(x1, y1, x2, y2);
  key[i] = kk;
  if (valid) atomicAdd(&hist16[((blockIdx.x & (NREP - 1)) << 16) + hslot(kk >> 16)], 1u);
}

// ---------------- 1b. reduce 8 replicas + UN-PERMUTE (hists is bin-ordered) --------
__global__ void __launch_bounds__(256) k_hsum(const uint32_t* __restrict__ hist16,
                                              uint32_t* __restrict__ hists) {
  int i = blockIdx.x * 256 + threadIdx.x;  // permuted slot, coalesced reads
  uint32_t s = 0;
#pragma unroll
  for (int r = 0; r < NREP; r++) s += hist16[(r << 16) + i];
  hists[hslot((uint32_t)i)] = s;           // scatter write, L2-absorbed
}

// ---------------- 2. scan 65536-bin histogram (linear layout now) ----------------
__global__ void __launch_bounds__(1024) k_scan16(const uint32_t* __restrict__ hists,
                                                 int* __restrict__ scal) {
  __shared__ unsigned short hh[65536];   // 128 KB
  __shared__ uint32_t part[1024];
  int t = threadIdx.x;
  const uint4* h4 = (const uint4*)hists;
#pragma unroll
  for (int k = 0; k < 16; k++) {
    uint4 v = h4[k * 1024 + t];
    uint32_t base = 4 * (k * 1024 + t);
    hh[base + 0] = (unsigned short)v.x;   // linear: no scatter, 2-way bank (free)
    hh[base + 1] = (unsigned short)v.y;
    hh[base + 2] = (unsigned short)v.z;
    hh[base + 3] = (unsigned short)v.w;
  }
  __syncthreads();
  uint32_t sum = 0;
  for (int b = 0; b < 64; b++) sum += hh[t * 64 + b];
  part[t] = sum;
  __syncthreads();
  for (int off = 1; off < 1024; off <<= 1) {
    uint32_t v = (t >= off) ? part[t - off] : 0;
    __syncthreads();
    part[t] += v;
    __syncthreads();
  }
  if (t == 1023) scal[4] = (int)part[1023];
  uint32_t excl = part[t] - sum;
  if (excl < TOPK && excl + sum >= TOPK) {
    uint32_t cum = excl;
    for (int b = 0; b < 64; b++) {
      uint32_t h = hh[t * 64 + b];
      if (cum < TOPK && cum + h >= TOPK) { scal[0] = t * 64 + b; scal[1] = (int)cum; break; }
      cum += h;
    }
  }
}

// ---------------- 3. 8-bit refinement histogram ----------------
__global__ void k_hist8(const uint32_t* __restrict__ key, const int* __restrict__ scal,
                        uint32_t* __restrict__ hist8) {
  int i = blockIdx.x * blockDim.x + threadIdx.x;
  if (i >= NN) return;
  uint32_t P = (uint32_t)scal[0];
  uint32_t kk = key[i];
  if ((kk >> 16) == P) atomicAdd(&hist8[(kk >> 8) & 0xFFu], 1u);
}

__global__ void __launch_bounds__(256) k_scan8(const uint32_t* __restrict__ hist8,
                                               int* __restrict__ scal) {
  __shared__ uint32_t part[256];
  int t = threadIdx.x;
  uint32_t h = hist8[t];
  part[t] = h;
  __syncthreads();
  for (int off = 1; off < 256; off <<= 1) {
    uint32_t v = (t >= off) ? part[t - off] : 0;
    __syncthreads();
    part[t] += v;
    __syncthreads();
  }
  uint32_t excl = part[t] - h;
  uint32_t cb = (uint32_t)scal[1];
  if (cb + excl < TOPK && cb + excl + h >= TOPK)
    scal[2] = (scal[0] << 8) | t;
}

// ---------------- 4. compact candidates ----------------
__global__ void k_compact(const uint32_t* __restrict__ key, int* __restrict__ scal,
                          unsigned long long* __restrict__ sortbuf) {
  __shared__ int lcnt, lbase;
  int t = threadIdx.x;
  int i = blockIdx.x * blockDim.x + t;
  if (t == 0) lcnt = 0;
  __syncthreads();
  bool sel = false;
  uint32_t kk = 0;
  int my = 0;
  if (i < NN) {
    uint32_t T24 = (uint32_t)scal[2];
    kk = key[i];
    if ((kk >> 8) <= T24) { sel = true; my = atomicAdd(&lcnt, 1); }
  }
  __syncthreads();
  if (t == 0 && lcnt > 0) lbase = atomicAdd(&scal[3], lcnt);
  __syncthreads();
  if (sel) {
    int pos = lbase + my;
    if (pos < SORTN) sortbuf[pos] = (((unsigned long long)kk) << 32) | (uint32_t)i;
  }
}

// ---------------- 5a. per-chunk bitonic sort ----------------
__global__ void __launch_bounds__(256) k_sortA(unsigned long long* __restrict__ sortbuf) {
  __shared__ unsigned long long sm[CSZ];
  int t = threadIdx.x;
  unsigned long long* chunk = sortbuf + (size_t)blockIdx.x * CSZ;
  sm[t] = chunk[t];
  sm[t + 256] = chunk[t + 256];
  __syncthreads();
  for (int k = 2; k <= CSZ; k <<= 1) {
    for (int j = k >> 1; j > 0; j >>= 1) {
      int i1 = ((t & ~(j - 1)) << 1) | (t & (j - 1));
      int i2 = i1 | j;
      bool up = ((i1 & k) == 0);
      unsigned long long a = sm[i1], b = sm[i2];
      if ((a > b) == up) { sm[i1] = b; sm[i2] = a; }
      __syncthreads();
    }
  }
  chunk[t] = sm[t];
  chunk[t + 256] = sm[t + 256];
}

// ---------------- 5b. stable multi-merge rank + scatter ----------------
__global__ void __launch_bounds__(256) k_sortB(const unsigned long long* __restrict__ sortbuf,
                                               const float4* __restrict__ roi,
                                               float4* __restrict__ selbox) {
  int g = blockIdx.x * 256 + threadIdx.x;
  int c = g >> 9, p = g & (CSZ - 1);
  unsigned long long val = sortbuf[g];
  int rank = p;
  for (int c2 = 0; c2 < NCHUNK; c2++) {
    if (c2 == c) continue;
    const unsigned long long* base = sortbuf + ((size_t)c2 << 9);
    bool le = (c2 < c);
    int pos = 0;
#pragma unroll
    for (int s = CSZ; s > 0; s >>= 1) {
      if (pos + s <= CSZ) {
        unsigned long long v = base[pos + s - 1];
        if (le ? (v <= val) : (v < val)) pos += s;
      }
    }
    rank += pos;
  }
  if (rank < (int)TOPK) {
    selbox[rank] = roi[(uint32_t)val];
  } else if (rank < KPAD) {
    selbox[rank] = make_float4(0.f, 0.f, 0.f, 0.f);
  }
}

// ---------------- 6. suppression: dense diag (intra-word) + sparse rows (inter) ----
__global__ void __launch_bounds__(64) k_mask(const float4* __restrict__ selbox,
                                             unsigned long long* __restrict__ diag,
                                             uint32_t* __restrict__ rcnt,
                                             unsigned short* __restrict__ rows) {
  int bi = blockIdx.x, bj = blockIdx.y;
  if (bj < bi) return;
  int t = threadIdx.x;
  __shared__ float4 jb[64];
  __shared__ float  ja[64];
  int j0 = bj * 64;
  float4 cb = selbox[j0 + t];
  jb[t] = cb;
  ja[t] = (cb.z - cb.x) * (cb.w - cb.y);
  __syncthreads();
  int i = bi * 64 + t;
  unsigned long long word = 0;
  if (i < (int)TOPK) {
    float4 bi4 = selbox[i];
    float ai = (bi4.z - bi4.x) * (bi4.w - bi4.y);
    for (int jj = 0; jj < 64; jj++) {
      int j = j0 + jj;
      float4 bb = jb[jj];
      float ltx = fmaxf(bi4.x, bb.x), lty = fmaxf(bi4.y, bb.y);
      float rbx = fminf(bi4.z, bb.z), rby = fminf(bi4.w, bb.w);
      float wx = fmaxf(rbx - ltx, 0.0f), wy = fmaxf(rby - lty, 0.0f);
      float inter = wx * wy;
      float iou = inter / (ai + ja[jj] - inter + 1e-9f);
      if (iou > 0.7f && j > i && j < (int)TOPK) word |= (1ull << jj);
    }
  }
  if (bi == bj) {
    diag[i] = word;                     // intra-word, dense (walk is cheap when 0)
    return;
  }
  if (word) {                           // inter-word: target word strictly later
    uint32_t n = (uint32_t)__popcll(word);
    uint32_t pos = atomicAdd(&rcnt[i], n);
    unsigned long long rem = word;
    while (rem && pos < RCAP) {
      int jj = (int)__builtin_ctzll(rem);
      rem &= rem - 1;
      rows[(size_t)i * RCAP + pos] = (unsigned short)(j0 + jj);
      pos++;
    }
  }
}

// ---------------- 7. greedy keep: single-wave word-ordered sparse pass ----------------
// Depth-independent exact greedy (R7 logic): process words 0..93 in order; per
// word: uniform keep read -> intra-word ballot walk (diag, usually 0 iters) ->
// lane-parallel application of the word's sparse inter-entries (targets are
// strictly later words). Single wave => LDS-FIFO ordering, zero barriers in
// the loop. Entries gathered i-ordered via R10's register-prefix scan, which
// also yields per-word offsets woff[].
__global__ void __launch_bounds__(256) k_seq(const unsigned long long* __restrict__ diag,
                                             const uint32_t* __restrict__ rcnt,
                                             const unsigned short* __restrict__ rows,
                                             const int* __restrict__ scal,
                                             const float4* __restrict__ selbox,
                                             float* __restrict__ out) {
  __shared__ unsigned long long dlds[KPAD];   // 48 KB
  __shared__ uint32_t elds[ELDS2];            // 48 KB packed (i<<16|j)
  __shared__ uint32_t woff[KW + 1];
  __shared__ uint32_t wtot[4];
  __shared__ uint32_t keep32[2 * KW];
  __shared__ uint32_t wcnt_s[KW], wrank[KW];
  __shared__ uint32_t carry_s;
  const int t = threadIdx.x, lane = t & 63, wv = t >> 6;

  // stage diag
  for (int i = t; i < KPAD / 2; i += 256)
    ((ulonglong2*)dlds)[i] = ((const ulonglong2*)diag)[i];

  // ordered gather: 24 rows/thread register prefix (R10, verified)
  uint32_t cnt[24], loc[24];
  uint32_t s = 0;
#pragma unroll
  for (int k = 0; k < 24; k++) {
    int r = t * 24 + k;
    uint32_t c = (r < KPAD) ? rcnt[r] : 0;
    c = (c > RCAP) ? RCAP : c;
    loc[k] = s; cnt[k] = c; s += c;
  }
  uint32_t pre = s;
#pragma unroll
  for (int off = 1; off < 64; off <<= 1) {
    uint32_t v = __shfl_up(pre, off);
    if (lane >= off) pre += v;
  }
  if (lane == 63) wtot[wv] = pre;
  __syncthreads();
  uint32_t wbase = 0;
  for (int w2 = 0; w2 < wv; w2++) wbase += wtot[w2];
  uint32_t excl = wbase + pre - s;
  // word-boundary offsets + total
#pragma unroll
  for (int k = 0; k < 24; k++) {
    int r = t * 24 + k;
    if (r < KPAD && (r & 63) == 0) woff[r >> 6] = excl + loc[k];
  }
  if (t == 255) woff[KW] = excl + s;
  // keep init from valid-prefix
  {
    int V = scal[4];
    if (V > (int)TOPK) V = (int)TOPK;
    if (t < 2 * KW) {
      int d = V - t * 32;
      keep32[t] = (d <= 0) ? 0u : ((d >= 32) ? 0xFFFFFFFFu : ((1u << d) - 1u));
    }
  }
  __syncthreads();
  // gather entries (i-ordered by construction)
#pragma unroll
  for (int k = 0; k < 24; k++) {
    int r = t * 24 + k;
    for (uint32_t q = 0; q < cnt[k]; q++) {
      uint32_t dst = excl + loc[k] + q;
      if (dst < ELDS2)
        elds[dst] = ((uint32_t)r << 16) | (uint32_t)rows[(size_t)r * RCAP + q];
    }
  }
  __syncthreads();

  // single-wave word-ordered pass
  if (t < 64) {
    unsigned long long mb = dlds[lane];     // diag rows of word 0
    for (int c = 0; c < KW; c++) {
      unsigned long long mbn = (c + 1 < KW) ? dlds[(c + 1) * 64 + lane] : 0ull;
      unsigned long long w =
          ((unsigned long long)keep32[2 * c + 1] << 32) | keep32[2 * c];
      // intra-word resolve (ballot walk; usually zero iterations)
      unsigned long long sup = __ballot(mb != 0);
      unsigned long long rem = w & sup;
      while (rem) {
        int b = (int)__builtin_ctzll(rem);
        uint32_t mlo = __builtin_amdgcn_readlane((uint32_t)mb, b);
        uint32_t mhi = __builtin_amdgcn_readlane((uint32_t)(mb >> 32), b);
        w &= ~(((unsigned long long)mhi << 32) | mlo);
        rem = (b >= 63) ? 0ull : (w & sup & (~0ull << (b + 1)));
      }
      if (lane == 0) {
        keep32[2 * c] = (uint32_t)w;
        keep32[2 * c + 1] = (uint32_t)(w >> 32);
      }
      // inter-word entries of word c, lane-parallel (targets strictly > c)
      uint32_t base = woff[c], endp = woff[c + 1];
      if (base > ELDS2) base = ELDS2;
      if (endp > ELDS2) endp = ELDS2;
      for (uint32_t k = base + (uint32_t)lane; k < endp; k += 64) {
        uint32_t e = elds[k];
        uint32_t i = e >> 16, j = e & 0xFFFFu;
        if ((w >> (i & 63)) & 1ull)
          atomicAnd(&keep32[j >> 5], ~(1u << (j & 31)));
      }
      mb = mbn;
    }
  }
  __syncthreads();

  // parallel rank of kept rows
  if (t < KW)
    wcnt_s[t] = (uint32_t)(__popc(keep32[2 * t]) + __popc(keep32[2 * t + 1]));
  __syncthreads();
  if (t < 64) {
    uint32_t v = wcnt_s[t], p2 = v;
#pragma unroll
    for (int off = 1; off < 64; off <<= 1) {
      uint32_t x = __shfl_up(p2, off);
      if (lane >= off) p2 += x;
    }
    wrank[t] = p2 - v;
    if (t == 63) carry_s = p2;
  }
  __syncthreads();
  if (t >= 64 && t < KW) {
    uint32_t v = wcnt_s[t], p2 = v;
#pragma unroll
    for (int off = 1; off < 64; off <<= 1) {
      uint32_t x = __shfl_up(p2, off);
      if (lane >= off) p2 += x;
    }
    wrank[t] = carry_s + p2 - v;
  }
  __syncthreads();
  for (int o = t; o < OUTK * 4; o += 256) out[o] = 0.0f;
  __syncthreads();
  for (int r = t; r < (int)TOPK; r += 256) {
    unsigned long long w =
        ((unsigned long long)keep32[2 * (r >> 6) + 1] << 32) | keep32[2 * (r >> 6)];
    int b = r & 63;
    if ((w >> b) & 1ull) {
      uint32_t rank = wrank[r >> 6] + (uint32_t)__popcll(w & ((1ull << b) - 1ull));
      if (rank < OUTK) {
        float4 bx = selbox[r];
        out[rank * 4 + 0] = bx.x;
        out[rank * 4 + 1] = bx.y;
        out[rank * 4 + 2] = bx.z;
        out[rank * 4 + 3] = bx.w;
      }
    }
  }
}

// ---------------- launch ----------------
extern "C" void kernel_launch(void* const* d_in, const int* in_sizes, int n_in,
                              void* d_out, int out_size, void* d_ws, size_t ws_size,
                              hipStream_t stream) {
  const float* cls    = (const float*)d_in[0];
  const float* reg    = (const float*)d_in[1];
  const float* anchor = (const float*)d_in[2];
  float* out = (float*)d_out;
  char* ws = (char*)d_ws;

  float4*   roi     = (float4*)(ws + OFF_ROI);
  uint32_t* key     = (uint32_t*)(ws + OFF_KEY);
  uint32_t* hist16  = (uint32_t*)(ws + OFF_HIST16);
  uint32_t* hists   = (uint32_t*)(ws + OFF_HISTS);
  uint32_t* hist8   = (uint32_t*)(ws + OFF_HIST8);
  int*      scal    = (int*)(ws + OFF_SCAL);
  uint32_t* rcnt    = (uint32_t*)(ws + OFF_RCNT);
  unsigned long long* sortbuf = (unsigned long long*)(ws + OFF_SORT);
  float4*   selbox  = (float4*)(ws + OFF_SELBOX);
  unsigned long long* diag = (unsigned long long*)(ws + OFF_DIAG);
  unsigned short* rows = (unsigned short*)(ws + OFF_ROWS);

  int blocks = (NN + 255) / 256;
  k_init<<<INIT_BLOCKS, 256, 0, stream>>>(ws);
  k_decode<<<blocks, 256, 0, stream>>>(cls, reg, anchor, roi, key, hist16);
  k_hsum<<<65536 / 256, 256, 0, stream>>>(hist16, hists);
  k_scan16<<<1, 1024, 0, stream>>>(hists, scal);
  k_hist8<<<blocks, 256, 0, stream>>>(key, scal, hist8);
  k_scan8<<<1, 256, 0, stream>>>(hist8, scal);
  k_compact<<<blocks, 256, 0, stream>>>(key, scal, sortbuf);
  k_sortA<<<NCHUNK, 256, 0, stream>>>(sortbuf);
  k_sortB<<<SORTN / 256, 256, 0, stream>>>(sortbuf, roi, selbox);
  k_mask<<<dim3(KW, KW), 64, 0, stream>>>(selbox, diag, rcnt, rows);
  k_seq<<<1, 256, 0, stream>>>(diag, rcnt, rows, scal, selbox, out);
}

// Round 14
// 162.862 us; speedup vs baseline: 1.7349x; 1.0036x over previous
//
#include <hip/hip_runtime.h>
#include <stdint.h>

#pragma clang fp contract(off)

#define NN    300000
#define TOPK  6000u
#define KW    94
#define KPAD  6016
#define SORTN 8192
#define NCHUNK 16
#define CSZ   512
#define OUTK  300
#define RCAP  64
#define ELDS2 12288
#define NREP  8

// ---------------- workspace layout (bytes) ----------------
static constexpr size_t OFF_ROI    = 0;                                   // NN*16
static constexpr size_t OFF_KEY    = OFF_ROI + (size_t)NN * 16;           // NN*4
static constexpr size_t OFF_HIST16 = ((OFF_KEY + (size_t)NN * 4 + 255) & ~(size_t)255); // NREP*65536*4
static constexpr size_t OFF_SCAL   = OFF_HIST16 + (size_t)NREP * 65536 * 4; // 256 B
static constexpr size_t OFF_RCNT   = OFF_SCAL + 256;                      // KPAD*4
static constexpr size_t ZERO_BYTES = (OFF_RCNT + (size_t)KPAD * 4) - OFF_HIST16;
static constexpr size_t OFF_HISTS  = OFF_RCNT + (size_t)KPAD * 4;         // 65536*4
static constexpr size_t OFF_SORT   = OFF_HISTS + 65536 * 4;               // SORTN*8
static constexpr size_t OFF_SELBOX = OFF_SORT + (size_t)SORTN * 8;        // KPAD*16
static constexpr size_t OFF_DIAG   = ((OFF_SELBOX + (size_t)KPAD * 16 + 255) & ~(size_t)255); // KPAD*8
static constexpr size_t OFF_ROWS   = OFF_DIAG + (size_t)KPAD * 8;         // KPAD*RCAP*2

// scal[]: [0]=P16 bin, [1]=count_below16, [3]=compact counter, [4]=valid total

static constexpr uint32_t ZG = (uint32_t)(ZERO_BYTES / 16);
static constexpr uint32_t SG = (uint32_t)(SORTN * 8 / 16);
static constexpr uint32_t INIT_BLOCKS = (ZG + SG + 255) / 256;

__device__ __forceinline__ uint32_t score_key(float s) {
  uint32_t u = __float_as_uint(s);
  u = (u >> 31) ? ~u : (u | 0x80000000u);
  return ~u;
}
__device__ __forceinline__ uint32_t hslot(uint32_t b) { return __brev(b) >> 16; }

// ---------------- 0. workspace init ----------------
__global__ void __launch_bounds__(256) k_init(char* __restrict__ ws) {
  uint32_t idx = blockIdx.x * 256 + threadIdx.x;
  if (idx < ZG) {
    ((uint4*)(ws + OFF_HIST16))[idx] = make_uint4(0u, 0u, 0u, 0u);
  } else if (idx < ZG + SG) {
    ((uint4*)(ws + OFF_SORT))[idx - ZG] = make_uint4(~0u, ~0u, ~0u, ~0u);
  }
}

// ---------------- 1. decode + key + replicated 16-bit histogram ----------------
__global__ void k_decode(const float* __restrict__ cls, const float* __restrict__ reg,
                         const float* __restrict__ anchor, float4* __restrict__ roi,
                         uint32_t* __restrict__ key, uint32_t* __restrict__ hist16) {
  int i = blockIdx.x * blockDim.x + threadIdx.x;
  if (i >= NN) return;
  float c0 = cls[2 * i], c1 = cls[2 * i + 1];
  float m  = fmaxf(c0, c1);
  float a0 = c0 - m, a1 = c1 - m;
  float tn = fminf(a0, a1);
  float e  = (float)exp((double)tn);
  float e0 = (a0 == 0.0f) ? 1.0f : e;
  float e1 = (a1 == 0.0f) ? 1.0f : e;
  float s  = e1 / (e0 + e1);

  float4 a = ((const float4*)anchor)[i];
  float acx = (a.x + a.z) * 0.5f;
  float acy = (a.y + a.w) * 0.5f;
  float aw  = a.z - a.x;
  float ah  = a.w - a.y;
  float4 r = ((const float4*)reg)[i];
  float cx = r.x * aw + acx;
  float cy = r.y * ah + acy;
  float w  = (float)exp((double)r.z) * aw;
  float h  = (float)exp((double)r.w) * ah;
  float x1 = cx - w * 0.5f, y1 = cy - h * 0.5f;
  float x2 = cx + w * 0.5f, y2 = cy + h * 0.5f;
  x1 = fminf(fmaxf(x1, 0.0f), 1.0f);
  y1 = fminf(fmaxf(y1, 0.0f), 1.0f);
  x2 = fminf(fmaxf(x2, 0.0f), 1.0f);
  y2 = fminf(fmaxf(y2, 0.0f), 1.0f);
  float ws_ = x2 - x1, hs_ = y2 - y1;
  bool valid = (hs_ >= 0.001f) && (ws_ >= 0.001f);
  float msc = valid ? s : -__builtin_inff();
  uint32_t kk = score_key(msc);

  roi[i] = make_float4(x1, y1, x2, y2);
  key[i] = kk;
  if (valid) atomicAdd(&hist16[((blockIdx.x & (NREP - 1)) << 16) + hslot(kk >> 16)], 1u);
}

// ---------------- 1b. reduce 8 replicas + un-permute ----------------
__global__ void __launch_bounds__(256) k_hsum(const uint32_t* __restrict__ hist16,
                                              uint32_t* __restrict__ hists) {
  int i = blockIdx.x * 256 + threadIdx.x;
  uint32_t s = 0;
#pragma unroll
  for (int r = 0; r < NREP; r++) s += hist16[(r << 16) + i];
  hists[hslot((uint32_t)i)] = s;
}

// ---------------- 2. scan 65536-bin histogram (linear) ----------------
__global__ void __launch_bounds__(1024) k_scan16(const uint32_t* __restrict__ hists,
                                                 int* __restrict__ scal) {
  __shared__ unsigned short hh[65536];
  __shared__ uint32_t part[1024];
  int t = threadIdx.x;
  const uint4* h4 = (const uint4*)hists;
#pragma unroll
  for (int k = 0; k < 16; k++) {
    uint4 v = h4[k * 1024 + t];
    uint32_t base = 4 * (k * 1024 + t);
    hh[base + 0] = (unsigned short)v.x;
    hh[base + 1] = (unsigned short)v.y;
    hh[base + 2] = (unsigned short)v.z;
    hh[base + 3] = (unsigned short)v.w;
  }
  __syncthreads();
  uint32_t sum = 0;
  for (int b = 0; b < 64; b++) sum += hh[t * 64 + b];
  part[t] = sum;
  __syncthreads();
  for (int off = 1; off < 1024; off <<= 1) {
    uint32_t v = (t >= off) ? part[t - off] : 0;
    __syncthreads();
    part[t] += v;
    __syncthreads();
  }
  if (t == 1023) scal[4] = (int)part[1023];
  uint32_t excl = part[t] - sum;
  if (excl < TOPK && excl + sum >= TOPK) {
    uint32_t cum = excl;
    for (int b = 0; b < 64; b++) {
      uint32_t h = hh[t * 64 + b];
      if (cum < TOPK && cum + h >= TOPK) { scal[0] = t * 64 + b; scal[1] = (int)cum; break; }
      cum += h;
    }
  }
}

// ---------------- 4. compact candidates: prefix16 <= P16 ----------------
// Boundary bin holds ~1200 keys (sigmoid scores: 50% of mass over 128 bins in
// [0.5,1)), so candidates < 7300 <= 8192: the full sort yields exact top-6000
// without the old 8-bit refinement level (2 kernels removed).
__global__ void k_compact(const uint32_t* __restrict__ key, int* __restrict__ scal,
                          unsigned long long* __restrict__ sortbuf) {
  __shared__ int lcnt, lbase;
  int t = threadIdx.x;
  int i = blockIdx.x * blockDim.x + t;
  if (t == 0) lcnt = 0;
  __syncthreads();
  bool sel = false;
  uint32_t kk = 0;
  int my = 0;
  if (i < NN) {
    uint32_t P = (uint32_t)scal[0];
    kk = key[i];
    if ((kk >> 16) <= P) { sel = true; my = atomicAdd(&lcnt, 1); }
  }
  __syncthreads();
  if (t == 0 && lcnt > 0) lbase = atomicAdd(&scal[3], lcnt);
  __syncthreads();
  if (sel) {
    int pos = lbase + my;
    if (pos < SORTN) sortbuf[pos] = (((unsigned long long)kk) << 32) | (uint32_t)i;
  }
}

// ---------------- 5a. per-chunk bitonic sort ----------------
__global__ void __launch_bounds__(256) k_sortA(unsigned long long* __restrict__ sortbuf) {
  __shared__ unsigned long long sm[CSZ];
  int t = threadIdx.x;
  unsigned long long* chunk = sortbuf + (size_t)blockIdx.x * CSZ;
  sm[t] = chunk[t];
  sm[t + 256] = chunk[t + 256];
  __syncthreads();
  for (int k = 2; k <= CSZ; k <<= 1) {
    for (int j = k >> 1; j > 0; j >>= 1) {
      int i1 = ((t & ~(j - 1)) << 1) | (t & (j - 1));
      int i2 = i1 | j;
      bool up = ((i1 & k) == 0);
      unsigned long long a = sm[i1], b = sm[i2];
      if ((a > b) == up) { sm[i1] = b; sm[i2] = a; }
      __syncthreads();
    }
  }
  chunk[t] = sm[t];
  chunk[t + 256] = sm[t + 256];
}

// ---------------- 5b. stable multi-merge rank + scatter ----------------
__global__ void __launch_bounds__(256) k_sortB(const unsigned long long* __restrict__ sortbuf,
                                               const float4* __restrict__ roi,
                                               float4* __restrict__ selbox) {
  int g = blockIdx.x * 256 + threadIdx.x;
  int c = g >> 9, p = g & (CSZ - 1);
  unsigned long long val = sortbuf[g];
  int rank = p;
  for (int c2 = 0; c2 < NCHUNK; c2++) {
    if (c2 == c) continue;
    const unsigned long long* base = sortbuf + ((size_t)c2 << 9);
    bool le = (c2 < c);
    int pos = 0;
#pragma unroll
    for (int s = CSZ; s > 0; s >>= 1) {
      if (pos + s <= CSZ) {
        unsigned long long v = base[pos + s - 1];
        if (le ? (v <= val) : (v < val)) pos += s;
      }
    }
    rank += pos;
  }
  if (rank < (int)TOPK) {
    selbox[rank] = roi[(uint32_t)val];
  } else if (rank < KPAD) {
    selbox[rank] = make_float4(0.f, 0.f, 0.f, 0.f);
  }
}

// ---------------- 6. suppression: dense diag (intra-word) + sparse rows (inter) ----
__global__ void __launch_bounds__(64) k_mask(const float4* __restrict__ selbox,
                                             unsigned long long* __restrict__ diag,
                                             uint32_t* __restrict__ rcnt,
                                             unsigned short* __restrict__ rows) {
  int bi = blockIdx.x, bj = blockIdx.y;
  if (bj < bi) return;
  int t = threadIdx.x;
  __shared__ float4 jb[64];
  __shared__ float  ja[64];
  int j0 = bj * 64;
  float4 cb = selbox[j0 + t];
  jb[t] = cb;
  ja[t] = (cb.z - cb.x) * (cb.w - cb.y);
  __syncthreads();
  int i = bi * 64 + t;
  unsigned long long word = 0;
  if (i < (int)TOPK) {
    float4 bi4 = selbox[i];
    float ai = (bi4.z - bi4.x) * (bi4.w - bi4.y);
    for (int jj = 0; jj < 64; jj++) {
      int j = j0 + jj;
      float4 bb = jb[jj];
      float ltx = fmaxf(bi4.x, bb.x), lty = fmaxf(bi4.y, bb.y);
      float rbx = fminf(bi4.z, bb.z), rby = fminf(bi4.w, bb.w);
      float wx = fmaxf(rbx - ltx, 0.0f), wy = fmaxf(rby - lty, 0.0f);
      float inter = wx * wy;
      float iou = inter / (ai + ja[jj] - inter + 1e-9f);
      if (iou > 0.7f && j > i && j < (int)TOPK) word |= (1ull << jj);
    }
  }
  if (bi == bj) {
    diag[i] = word;
    return;
  }
  if (word) {
    uint32_t n = (uint32_t)__popcll(word);
    uint32_t pos = atomicAdd(&rcnt[i], n);
    unsigned long long rem = word;
    while (rem && pos < RCAP) {
      int jj = (int)__builtin_ctzll(rem);
      rem &= rem - 1;
      rows[(size_t)i * RCAP + pos] = (unsigned short)(j0 + jj);
      pos++;
    }
  }
}

// ---------------- 7. greedy keep: word-ordered pass, ONE in-chain LDS read/word ------
// Per word c the ONLY dependent LDS op is the broadcast pend read (~120cyc).
// Diag row + <=128 entries (2 reg slots/lane) prefetched one word ahead; woff
// boundaries register-resident (readlane); entry application = lane-parallel
// register tests + fire-and-forget atomicOr into pend (same-wave LDS FIFO
// makes later pend reads see them - proven R9/R13). keep32 writes are
// out-of-chain (only read after the pass).
__global__ void __launch_bounds__(256) k_seq(const unsigned long long* __restrict__ diag,
                                             const uint32_t* __restrict__ rcnt,
                                             const unsigned short* __restrict__ rows,
                                             const int* __restrict__ scal,
                                             const float4* __restrict__ selbox,
                                             float* __restrict__ out) {
  __shared__ unsigned long long dlds[KPAD];   // 48 KB
  __shared__ uint32_t elds[ELDS2];            // 48 KB packed (i<<16|j), i-ordered
  __shared__ uint32_t woff_s[KW + 1];
  __shared__ uint32_t wtot[4];
  __shared__ uint32_t pend32[2 * KW];         // suppression masks (atomicOr)
  __shared__ uint32_t keep32[2 * KW];         // final keep words
  __shared__ uint32_t wcnt_s[KW], wrank[KW], carry_s;
  const int t = threadIdx.x, lane = t & 63, wv = t >> 6;

  for (int i = t; i < KPAD / 2; i += 256)
    ((ulonglong2*)dlds)[i] = ((const ulonglong2*)diag)[i];
  if (t < 2 * KW) pend32[t] = 0;

  // ordered gather (register-prefix, verified R10/R13): 24 rows/thread
  uint32_t cnt[24], loc[24];
  uint32_t s = 0;
#pragma unroll
  for (int k = 0; k < 24; k++) {
    int r = t * 24 + k;
    uint32_t c = (r < KPAD) ? rcnt[r] : 0;
    c = (c > RCAP) ? RCAP : c;
    loc[k] = s; cnt[k] = c; s += c;
  }
  uint32_t pre = s;
#pragma unroll
  for (int off = 1; off < 64; off <<= 1) {
    uint32_t v = __shfl_up(pre, off);
    if (lane >= off) pre += v;
  }
  if (lane == 63) wtot[wv] = pre;
  __syncthreads();
  uint32_t wbase = 0;
  for (int w2 = 0; w2 < wv; w2++) wbase += wtot[w2];
  uint32_t excl = wbase + pre - s;
#pragma unroll
  for (int k = 0; k < 24; k++) {
    int r = t * 24 + k;
    if (r < KPAD && (r & 63) == 0) woff_s[r >> 6] = excl + loc[k];
  }
  if (t == 255) woff_s[KW] = excl + s;
#pragma unroll
  for (int k = 0; k < 24; k++) {
    int r = t * 24 + k;
    for (uint32_t q = 0; q < cnt[k]; q++) {
      uint32_t dst = excl + loc[k] + q;
      if (dst < ELDS2)
        elds[dst] = ((uint32_t)r << 16) | (uint32_t)rows[(size_t)r * RCAP + q];
    }
  }
  __syncthreads();

  if (t < 64) {
    // woff into registers: wo0 = woff[lane], wo1 = woff[64+lane] (lanes 0..30)
    uint32_t wo0 = woff_s[lane];
    uint32_t wo1 = woff_s[(64 + lane <= KW) ? (64 + lane) : KW];
    int V = scal[4];
    if (V > (int)TOPK) V = (int)TOPK;

    // prologue: word 0 state
    unsigned long long mb = dlds[lane];
    uint32_t base = woff_s[0], endp = woff_s[1];
    if (base > ELDS2) base = ELDS2;
    if (endp > ELDS2) endp = ELDS2;
    uint32_t en0 = elds[(base + lane < ELDS2) ? (base + lane) : (ELDS2 - 1)];
    uint32_t en1 = elds[(base + 64 + lane < ELDS2) ? (base + 64 + lane) : (ELDS2 - 1)];

    for (int c = 0; c < KW; c++) {
      // prefetch word c+1 (static data; latency hides under this word's chain)
      unsigned long long mbn = 0;
      uint32_t basen = 0, endpn = 0, en0n = 0, en1n = 0;
      if (c + 1 < KW) {
        mbn = dlds[(c + 1) * 64 + lane];
        basen = (c + 1 < 64) ? __builtin_amdgcn_readlane(wo0, c + 1)
                             : __builtin_amdgcn_readlane(wo1, c + 1 - 64);
        endpn = (c + 2 < 64) ? __builtin_amdgcn_readlane(wo0, c + 2)
                             : __builtin_amdgcn_readlane(wo1, c + 2 - 64);
        if (basen > ELDS2) basen = ELDS2;
        if (endpn > ELDS2) endpn = ELDS2;
        en0n = elds[(basen + lane < ELDS2) ? (basen + lane) : (ELDS2 - 1)];
        en1n = elds[(basen + 64 + lane < ELDS2) ? (basen + 64 + lane) : (ELDS2 - 1)];
      }
      // the ONE in-chain LDS read: pend for word c (uniform addr -> broadcast)
      uint32_t plo = pend32[2 * c], phi = pend32[2 * c + 1];
      int d = V - c * 64;
      unsigned long long vinit =
          (d <= 0) ? 0ull : ((d >= 64) ? ~0ull : ((1ull << d) - 1));
      unsigned long long w = vinit & ~(((unsigned long long)phi << 32) | plo);
      // intra-word resolve (register diag, usually 0 iterations)
      unsigned long long sup = __ballot(mb != 0);
      unsigned long long rem = w & sup;
      while (rem) {
        int b = (int)__builtin_ctzll(rem);
        uint32_t mlo = __builtin_amdgcn_readlane((uint32_t)mb, b);
        uint32_t mhi = __builtin_amdgcn_readlane((uint32_t)(mb >> 32), b);
        w &= ~(((unsigned long long)mhi << 32) | mlo);
        rem = (b >= 63) ? 0ull : (w & sup & (~0ull << (b + 1)));
      }
      if (lane == 0) {                      // out-of-chain (read only after pass)
        keep32[2 * c] = (uint32_t)w;
        keep32[2 * c + 1] = (uint32_t)(w >> 32);
      }
      // entries of word c: lane-parallel register tests, fire-and-forget OR
      uint32_t cw = endp - base;
      if ((uint32_t)lane < cw) {
        uint32_t i = en0 >> 16, j = en0 & 0xFFFFu;
        if ((w >> (i & 63)) & 1ull) atomicOr(&pend32[j >> 5], 1u << (j & 31));
      }
      if ((uint32_t)(64 + lane) < cw) {
        uint32_t i = en1 >> 16, j = en1 & 0xFFFFu;
        if ((w >> (i & 63)) & 1ull) atomicOr(&pend32[j >> 5], 1u << (j & 31));
      }
      for (uint32_t k = base + 128 + lane; k < endp; k += 64) {  // rare overflow
        uint32_t e = elds[k];
        uint32_t i = e >> 16, j = e & 0xFFFFu;
        if ((w >> (i & 63)) & 1ull) atomicOr(&pend32[j >> 5], 1u << (j & 31));
      }
      mb = mbn; base = basen; endp = endpn; en0 = en0n; en1 = en1n;
    }
  }
  __syncthreads();

  // parallel rank + output
  if (t < KW)
    wcnt_s[t] = (uint32_t)(__popc(keep32[2 * t]) + __popc(keep32[2 * t + 1]));
  __syncthreads();
  if (t < 64) {
    uint32_t v = wcnt_s[t], p2 = v;
#pragma unroll
    for (int off = 1; off < 64; off <<= 1) {
      uint32_t x = __shfl_up(p2, off);
      if (lane >= off) p2 += x;
    }
    wrank[t] = p2 - v;
    if (t == 63) carry_s = p2;
  }
  __syncthreads();
  if (t >= 64 && t < KW) {
    uint32_t v = wcnt_s[t], p2 = v;
#pragma unroll
    for (int off = 1; off < 64; off <<= 1) {
      uint32_t x = __shfl_up(p2, off);
      if (lane >= off) p2 += x;
    }
    wrank[t] = carry_s + p2 - v;
  }
  __syncthreads();
  for (int o = t; o < OUTK * 4; o += 256) out[o] = 0.0f;
  __syncthreads();
  for (int r = t; r < (int)TOPK; r += 256) {
    unsigned long long w =
        ((unsigned long long)keep32[2 * (r >> 6) + 1] << 32) | keep32[2 * (r >> 6)];
    int b = r & 63;
    if ((w >> b) & 1ull) {
      uint32_t rank = wrank[r >> 6] + (uint32_t)__popcll(w & ((1ull << b) - 1ull));
      if (rank < OUTK) {
        float4 bx = selbox[r];
        out[rank * 4 + 0] = bx.x;
        out[rank * 4 + 1] = bx.y;
        out[rank * 4 + 2] = bx.z;
        out[rank * 4 + 3] = bx.w;
      }
    }
  }
}

// ---------------- launch ----------------
extern "C" void kernel_launch(void* const* d_in, const int* in_sizes, int n_in,
                              void* d_out, int out_size, void* d_ws, size_t ws_size,
                              hipStream_t stream) {
  const float* cls    = (const float*)d_in[0];
  const float* reg    = (const float*)d_in[1];
  const float* anchor = (const float*)d_in[2];
  float* out = (float*)d_out;
  char* ws = (char*)d_ws;

  float4*   roi     = (float4*)(ws + OFF_ROI);
  uint32_t* key     = (uint32_t*)(ws + OFF_KEY);
  uint32_t* hist16  = (uint32_t*)(ws + OFF_HIST16);
  uint32_t* hists   = (uint32_t*)(ws + OFF_HISTS);
  int*      scal    = (int*)(ws + OFF_SCAL);
  uint32_t* rcnt    = (uint32_t*)(ws + OFF_RCNT);
  unsigned long long* sortbuf = (unsigned long long*)(ws + OFF_SORT);
  float4*   selbox  = (float4*)(ws + OFF_SELBOX);
  unsigned long long* diag = (unsigned long long*)(ws + OFF_DIAG);
  unsigned short* rows = (unsigned short*)(ws + OFF_ROWS);

  int blocks = (NN + 255) / 256;
  k_init<<<INIT_BLOCKS, 256, 0, stream>>>(ws);
  k_decode<<<blocks, 256, 0, stream>>>(cls, reg, anchor, roi, key, hist16);
  k_hsum<<<65536 / 256, 256, 0, stream>>>(hist16, hists);
  k_scan16<<<1, 1024, 0, stream>>>(hists, scal);
  k_compact<<<blocks, 256, 0, stream>>>(key, scal, sortbuf);
  k_sortA<<<NCHUNK, 256, 0, stream>>>(sortbuf);
  k_sortB<<<SORTN / 256, 256, 0, stream>>>(sortbuf, roi, selbox);
  k_mask<<<dim3(KW, KW), 64, 0, stream>>>(selbox, diag, rcnt, rows);
  k_seq<<<1, 256, 0, stream>>>(diag, rcnt, rows, scal, selbox, out);
}

// Round 15
// 132.539 us; speedup vs baseline: 2.1318x; 1.2288x over previous
//
#include <hip/hip_runtime.h>
#include <stdint.h>

#pragma clang fp contract(off)

#define NN    300000
#define TOPK  6000u
#define KW    94
#define KPAD  6016
#define SORTN 8192
#define NCHUNK 16
#define CSZ   512
#define OUTK  300
#define RCAP  64
#define ELDS2 12288
#define NREP  8

// ---------------- workspace layout (bytes) ----------------
static constexpr size_t OFF_ROI    = 0;                                   // NN*16
static constexpr size_t OFF_KEY    = OFF_ROI + (size_t)NN * 16;           // NN*4
static constexpr size_t OFF_HIST16 = ((OFF_KEY + (size_t)NN * 4 + 255) & ~(size_t)255); // NREP*65536*4
static constexpr size_t OFF_SCAL   = OFF_HIST16 + (size_t)NREP * 65536 * 4; // 256 B
static constexpr size_t OFF_RCNT   = OFF_SCAL + 256;                      // KPAD*4
static constexpr size_t ZERO_BYTES = (OFF_RCNT + (size_t)KPAD * 4) - OFF_HIST16;
static constexpr size_t OFF_HISTS  = OFF_RCNT + (size_t)KPAD * 4;         // 65536*4
static constexpr size_t OFF_SORT   = OFF_HISTS + 65536 * 4;               // SORTN*8
static constexpr size_t OFF_SELBOX = OFF_SORT + (size_t)SORTN * 8;        // KPAD*16
static constexpr size_t OFF_DIAG   = ((OFF_SELBOX + (size_t)KPAD * 16 + 255) & ~(size_t)255); // KPAD*8
static constexpr size_t OFF_ROWS   = OFF_DIAG + (size_t)KPAD * 8;         // KPAD*RCAP*2

// scal[]: [0]=P16 bin, [1]=count_below16, [3]=compact counter, [4]=valid total

static constexpr uint32_t ZG = (uint32_t)(ZERO_BYTES / 16);
static constexpr uint32_t SG = (uint32_t)(SORTN * 8 / 16);
static constexpr uint32_t INIT_BLOCKS = (ZG + SG + 255) / 256;

__device__ __forceinline__ uint32_t score_key(float s) {
  uint32_t u = __float_as_uint(s);
  u = (u >> 31) ? ~u : (u | 0x80000000u);
  return ~u;
}
__device__ __forceinline__ uint32_t hslot(uint32_t b) { return __brev(b) >> 16; }

// ---------------- 0. workspace init ----------------
__global__ void __launch_bounds__(256) k_init(char* __restrict__ ws) {
  uint32_t idx = blockIdx.x * 256 + threadIdx.x;
  if (idx < ZG) {
    ((uint4*)(ws + OFF_HIST16))[idx] = make_uint4(0u, 0u, 0u, 0u);
  } else if (idx < ZG + SG) {
    ((uint4*)(ws + OFF_SORT))[idx - ZG] = make_uint4(~0u, ~0u, ~0u, ~0u);
  }
}

// ---------------- 1. decode + key + replicated 16-bit histogram ----------------
__global__ void k_decode(const float* __restrict__ cls, const float* __restrict__ reg,
                         const float* __restrict__ anchor, float4* __restrict__ roi,
                         uint32_t* __restrict__ key, uint32_t* __restrict__ hist16) {
  int i = blockIdx.x * blockDim.x + threadIdx.x;
  if (i >= NN) return;
  float c0 = cls[2 * i], c1 = cls[2 * i + 1];
  float m  = fmaxf(c0, c1);
  float a0 = c0 - m, a1 = c1 - m;
  float tn = fminf(a0, a1);
  float e  = (float)exp((double)tn);
  float e0 = (a0 == 0.0f) ? 1.0f : e;
  float e1 = (a1 == 0.0f) ? 1.0f : e;
  float s  = e1 / (e0 + e1);

  float4 a = ((const float4*)anchor)[i];
  float acx = (a.x + a.z) * 0.5f;
  float acy = (a.y + a.w) * 0.5f;
  float aw  = a.z - a.x;
  float ah  = a.w - a.y;
  float4 r = ((const float4*)reg)[i];
  float cx = r.x * aw + acx;
  float cy = r.y * ah + acy;
  float w  = (float)exp((double)r.z) * aw;
  float h  = (float)exp((double)r.w) * ah;
  float x1 = cx - w * 0.5f, y1 = cy - h * 0.5f;
  float x2 = cx + w * 0.5f, y2 = cy + h * 0.5f;
  x1 = fminf(fmaxf(x1, 0.0f), 1.0f);
  y1 = fminf(fmaxf(y1, 0.0f), 1.0f);
  x2 = fminf(fmaxf(x2, 0.0f), 1.0f);
  y2 = fminf(fmaxf(y2, 0.0f), 1.0f);
  float ws_ = x2 - x1, hs_ = y2 - y1;
  bool valid = (hs_ >= 0.001f) && (ws_ >= 0.001f);
  float msc = valid ? s : -__builtin_inff();
  uint32_t kk = score_key(msc);

  roi[i] = make_float4(x1, y1, x2, y2);
  key[i] = kk;
  if (valid) atomicAdd(&hist16[((blockIdx.x & (NREP - 1)) << 16) + hslot(kk >> 16)], 1u);
}

// ---------------- 1b. reduce 8 replicas + un-permute ----------------
__global__ void __launch_bounds__(256) k_hsum(const uint32_t* __restrict__ hist16,
                                              uint32_t* __restrict__ hists) {
  int i = blockIdx.x * 256 + threadIdx.x;
  uint32_t s = 0;
#pragma unroll
  for (int r = 0; r < NREP; r++) s += hist16[(r << 16) + i];
  hists[hslot((uint32_t)i)] = s;
}

// ---------------- 2. scan 65536-bin histogram (linear) ----------------
__global__ void __launch_bounds__(1024) k_scan16(const uint32_t* __restrict__ hists,
                                                 int* __restrict__ scal) {
  __shared__ unsigned short hh[65536];
  __shared__ uint32_t part[1024];
  int t = threadIdx.x;
  const uint4* h4 = (const uint4*)hists;
#pragma unroll
  for (int k = 0; k < 16; k++) {
    uint4 v = h4[k * 1024 + t];
    uint32_t base = 4 * (k * 1024 + t);
    hh[base + 0] = (unsigned short)v.x;
    hh[base + 1] = (unsigned short)v.y;
    hh[base + 2] = (unsigned short)v.z;
    hh[base + 3] = (unsigned short)v.w;
  }
  __syncthreads();
  uint32_t sum = 0;
  for (int b = 0; b < 64; b++) sum += hh[t * 64 + b];
  part[t] = sum;
  __syncthreads();
  for (int off = 1; off < 1024; off <<= 1) {
    uint32_t v = (t >= off) ? part[t - off] : 0;
    __syncthreads();
    part[t] += v;
    __syncthreads();
  }
  if (t == 1023) scal[4] = (int)part[1023];
  uint32_t excl = part[t] - sum;
  if (excl < TOPK && excl + sum >= TOPK) {
    uint32_t cum = excl;
    for (int b = 0; b < 64; b++) {
      uint32_t h = hh[t * 64 + b];
      if (cum < TOPK && cum + h >= TOPK) { scal[0] = t * 64 + b; scal[1] = (int)cum; break; }
      cum += h;
    }
  }
}

// ---------------- 4. compact candidates: prefix16 <= P16 ----------------
__global__ void k_compact(const uint32_t* __restrict__ key, int* __restrict__ scal,
                          unsigned long long* __restrict__ sortbuf) {
  __shared__ int lcnt, lbase;
  int t = threadIdx.x;
  int i = blockIdx.x * blockDim.x + t;
  if (t == 0) lcnt = 0;
  __syncthreads();
  bool sel = false;
  uint32_t kk = 0;
  int my = 0;
  if (i < NN) {
    uint32_t P = (uint32_t)scal[0];
    kk = key[i];
    if ((kk >> 16) <= P) { sel = true; my = atomicAdd(&lcnt, 1); }
  }
  __syncthreads();
  if (t == 0 && lcnt > 0) lbase = atomicAdd(&scal[3], lcnt);
  __syncthreads();
  if (sel) {
    int pos = lbase + my;
    if (pos < SORTN) sortbuf[pos] = (((unsigned long long)kk) << 32) | (uint32_t)i;
  }
}

// ---------------- 5a. per-chunk bitonic sort ----------------
__global__ void __launch_bounds__(256) k_sortA(unsigned long long* __restrict__ sortbuf) {
  __shared__ unsigned long long sm[CSZ];
  int t = threadIdx.x;
  unsigned long long* chunk = sortbuf + (size_t)blockIdx.x * CSZ;
  sm[t] = chunk[t];
  sm[t + 256] = chunk[t + 256];
  __syncthreads();
  for (int k = 2; k <= CSZ; k <<= 1) {
    for (int j = k >> 1; j > 0; j >>= 1) {
      int i1 = ((t & ~(j - 1)) << 1) | (t & (j - 1));
      int i2 = i1 | j;
      bool up = ((i1 & k) == 0);
      unsigned long long a = sm[i1], b = sm[i2];
      if ((a > b) == up) { sm[i1] = b; sm[i2] = a; }
      __syncthreads();
    }
  }
  chunk[t] = sm[t];
  chunk[t + 256] = sm[t + 256];
}

// ---------------- 5b. stable multi-merge rank + scatter ----------------
__global__ void __launch_bounds__(256) k_sortB(const unsigned long long* __restrict__ sortbuf,
                                               const float4* __restrict__ roi,
                                               float4* __restrict__ selbox) {
  int g = blockIdx.x * 256 + threadIdx.x;
  int c = g >> 9, p = g & (CSZ - 1);
  unsigned long long val = sortbuf[g];
  int rank = p;
  for (int c2 = 0; c2 < NCHUNK; c2++) {
    if (c2 == c) continue;
    const unsigned long long* base = sortbuf + ((size_t)c2 << 9);
    bool le = (c2 < c);
    int pos = 0;
#pragma unroll
    for (int s = CSZ; s > 0; s >>= 1) {
      if (pos + s <= CSZ) {
        unsigned long long v = base[pos + s - 1];
        if (le ? (v <= val) : (v < val)) pos += s;
      }
    }
    rank += pos;
  }
  if (rank < (int)TOPK) {
    selbox[rank] = roi[(uint32_t)val];
  } else if (rank < KPAD) {
    selbox[rank] = make_float4(0.f, 0.f, 0.f, 0.f);
  }
}

// ---------------- 6. suppression: dense diag (intra-word) + sparse rows (inter) ----
__global__ void __launch_bounds__(64) k_mask(const float4* __restrict__ selbox,
                                             unsigned long long* __restrict__ diag,
                                             uint32_t* __restrict__ rcnt,
                                             unsigned short* __restrict__ rows) {
  int bi = blockIdx.x, bj = blockIdx.y;
  if (bj < bi) return;
  int t = threadIdx.x;
  __shared__ float4 jb[64];
  __shared__ float  ja[64];
  int j0 = bj * 64;
  float4 cb = selbox[j0 + t];
  jb[t] = cb;
  ja[t] = (cb.z - cb.x) * (cb.w - cb.y);
  __syncthreads();
  int i = bi * 64 + t;
  unsigned long long word = 0;
  if (i < (int)TOPK) {
    float4 bi4 = selbox[i];
    float ai = (bi4.z - bi4.x) * (bi4.w - bi4.y);
    for (int jj = 0; jj < 64; jj++) {
      int j = j0 + jj;
      float4 bb = jb[jj];
      float ltx = fmaxf(bi4.x, bb.x), lty = fmaxf(bi4.y, bb.y);
      float rbx = fminf(bi4.z, bb.z), rby = fminf(bi4.w, bb.w);
      float wx = fmaxf(rbx - ltx, 0.0f), wy = fmaxf(rby - lty, 0.0f);
      float inter = wx * wy;
      float iou = inter / (ai + ja[jj] - inter + 1e-9f);
      if (iou > 0.7f && j > i && j < (int)TOPK) word |= (1ull << jj);
    }
  }
  if (bi == bj) {
    diag[i] = word;
    return;
  }
  if (word) {
    uint32_t n = (uint32_t)__popcll(word);
    uint32_t pos = atomicAdd(&rcnt[i], n);
    unsigned long long rem = word;
    while (rem && pos < RCAP) {
      int jj = (int)__builtin_ctzll(rem);
      rem &= rem - 1;
      rows[(size_t)i * RCAP + pos] = (unsigned short)(j0 + jj);
      pos++;
    }
  }
}

// ---------------- 7. greedy keep: word-ordered pass with EARLY EXIT ----------------
// Prefix closure: keep[i] depends only on keep[j<i], and the output needs only
// the first OUTK kept boxes. Run the word-ordered pass (R13/R14 logic) with a
// running keep count; break once cum >= OUTK (typically word ~5-8 of 94) and
// zero all later keep words (they can only produce ranks >= OUTK, which the
// output discards -> bit-identical). Diag rows prefetched from GLOBAL one word
// ahead (no 48KB staging). Worst case degenerates to the full 94-word pass.
__global__ void __launch_bounds__(256) k_seq(const unsigned long long* __restrict__ diag,
                                             const uint32_t* __restrict__ rcnt,
                                             const unsigned short* __restrict__ rows,
                                             const int* __restrict__ scal,
                                             const float4* __restrict__ selbox,
                                             float* __restrict__ out) {
  __shared__ uint32_t elds[ELDS2];            // 48 KB packed (i<<16|j), i-ordered
  __shared__ uint32_t woff_s[KW + 1];
  __shared__ uint32_t wtot[4];
  __shared__ uint32_t pend32[2 * KW];         // suppression masks (atomicOr)
  __shared__ uint32_t keep32[2 * KW];         // final keep words
  __shared__ uint32_t wcnt_s[KW], wrank[KW], carry_s;
  const int t = threadIdx.x, lane = t & 63, wv = t >> 6;

  if (t < 2 * KW) pend32[t] = 0;

  // ordered gather (register-prefix, verified R10/R13): 24 rows/thread
  uint32_t cnt[24], loc[24];
  uint32_t s = 0;
#pragma unroll
  for (int k = 0; k < 24; k++) {
    int r = t * 24 + k;
    uint32_t c = (r < KPAD) ? rcnt[r] : 0;
    c = (c > RCAP) ? RCAP : c;
    loc[k] = s; cnt[k] = c; s += c;
  }
  uint32_t pre = s;
#pragma unroll
  for (int off = 1; off < 64; off <<= 1) {
    uint32_t v = __shfl_up(pre, off);
    if (lane >= off) pre += v;
  }
  if (lane == 63) wtot[wv] = pre;
  __syncthreads();
  uint32_t wbase = 0;
  for (int w2 = 0; w2 < wv; w2++) wbase += wtot[w2];
  uint32_t excl = wbase + pre - s;
#pragma unroll
  for (int k = 0; k < 24; k++) {
    int r = t * 24 + k;
    if (r < KPAD && (r & 63) == 0) woff_s[r >> 6] = excl + loc[k];
  }
  if (t == 255) woff_s[KW] = excl + s;
#pragma unroll
  for (int k = 0; k < 24; k++) {
    int r = t * 24 + k;
    for (uint32_t q = 0; q < cnt[k]; q++) {
      uint32_t dst = excl + loc[k] + q;
      if (dst < ELDS2)
        elds[dst] = ((uint32_t)r << 16) | (uint32_t)rows[(size_t)r * RCAP + q];
    }
  }
  __syncthreads();

  if (t < 64) {
    uint32_t wo0 = woff_s[lane];
    uint32_t wo1 = woff_s[(64 + lane <= KW) ? (64 + lane) : KW];
    int V = scal[4];
    if (V > (int)TOPK) V = (int)TOPK;

    // prologue: word 0 state (diag from GLOBAL; elds prefetch)
    unsigned long long mb = diag[lane];
    uint32_t base = woff_s[0], endp = woff_s[1];
    if (base > ELDS2) base = ELDS2;
    if (endp > ELDS2) endp = ELDS2;
    uint32_t en0 = elds[(base + lane < ELDS2) ? (base + lane) : (ELDS2 - 1)];
    uint32_t en1 = elds[(base + 64 + lane < ELDS2) ? (base + 64 + lane) : (ELDS2 - 1)];

    uint32_t cum = 0;
    int cut = KW - 1;
    for (int c = 0; c < KW; c++) {
      // prefetch word c+1 (global diag + LDS entries; out of chain)
      unsigned long long mbn = 0;
      uint32_t basen = 0, endpn = 0, en0n = 0, en1n = 0;
      if (c + 1 < KW) {
        mbn = diag[(c + 1) * 64 + lane];
        basen = (c + 1 < 64) ? __builtin_amdgcn_readlane(wo0, c + 1)
                             : __builtin_amdgcn_readlane(wo1, c + 1 - 64);
        endpn = (c + 2 < 64) ? __builtin_amdgcn_readlane(wo0, c + 2)
                             : __builtin_amdgcn_readlane(wo1, c + 2 - 64);
        if (basen > ELDS2) basen = ELDS2;
        if (endpn > ELDS2) endpn = ELDS2;
        en0n = elds[(basen + lane < ELDS2) ? (basen + lane) : (ELDS2 - 1)];
        en1n = elds[(basen + 64 + lane < ELDS2) ? (basen + 64 + lane) : (ELDS2 - 1)];
      }
      // the one in-chain LDS read: pend for word c (uniform -> broadcast)
      uint32_t plo = pend32[2 * c], phi = pend32[2 * c + 1];
      int d = V - c * 64;
      unsigned long long vinit =
          (d <= 0) ? 0ull : ((d >= 64) ? ~0ull : ((1ull << d) - 1));
      unsigned long long w = vinit & ~(((unsigned long long)phi << 32) | plo);
      // intra-word resolve (register diag, usually 0 iterations)
      unsigned long long sup = __ballot(mb != 0);
      unsigned long long rem = w & sup;
      while (rem) {
        int b = (int)__builtin_ctzll(rem);
        uint32_t mlo = __builtin_amdgcn_readlane((uint32_t)mb, b);
        uint32_t mhi = __builtin_amdgcn_readlane((uint32_t)(mb >> 32), b);
        w &= ~(((unsigned long long)mhi << 32) | mlo);
        rem = (b >= 63) ? 0ull : (w & sup & (~0ull << (b + 1)));
      }
      if (lane == 0) {
        keep32[2 * c] = (uint32_t)w;
        keep32[2 * c + 1] = (uint32_t)(w >> 32);
      }
      // EARLY EXIT: first OUTK keeps are fully determined (prefix closure);
      // later words can only contribute ranks >= OUTK, which output discards.
      cum += (uint32_t)__popcll(w);
      if (cum >= OUTK) { cut = c; break; }
      // entries of word c: lane-parallel register tests, fire-and-forget OR
      uint32_t cw = endp - base;
      if ((uint32_t)lane < cw) {
        uint32_t i = en0 >> 16, j = en0 & 0xFFFFu;
        if ((w >> (i & 63)) & 1ull) atomicOr(&pend32[j >> 5], 1u << (j & 31));
      }
      if ((uint32_t)(64 + lane) < cw) {
        uint32_t i = en1 >> 16, j = en1 & 0xFFFFu;
        if ((w >> (i & 63)) & 1ull) atomicOr(&pend32[j >> 5], 1u << (j & 31));
      }
      for (uint32_t k = base + 128 + lane; k < endp; k += 64) {  // rare overflow
        uint32_t e = elds[k];
        uint32_t i = e >> 16, j = e & 0xFFFFu;
        if ((w >> (i & 63)) & 1ull) atomicOr(&pend32[j >> 5], 1u << (j & 31));
      }
      mb = mbn; base = basen; endp = endpn; en0 = en0n; en1 = en1n;
    }
    // zero keep words beyond the cutoff (never produce ranks < OUTK)
    for (int wz = cut + 1 + lane; wz < KW; wz += 64) {
      keep32[2 * wz] = 0;
      keep32[2 * wz + 1] = 0;
    }
  }
  __syncthreads();

  // parallel rank + output
  if (t < KW)
    wcnt_s[t] = (uint32_t)(__popc(keep32[2 * t]) + __popc(keep32[2 * t + 1]));
  __syncthreads();
  if (t < 64) {
    uint32_t v = wcnt_s[t], p2 = v;
#pragma unroll
    for (int off = 1; off < 64; off <<= 1) {
      uint32_t x = __shfl_up(p2, off);
      if (lane >= off) p2 += x;
    }
    wrank[t] = p2 - v;
    if (t == 63) carry_s = p2;
  }
  __syncthreads();
  if (t >= 64 && t < KW) {
    uint32_t v = wcnt_s[t], p2 = v;
#pragma unroll
    for (int off = 1; off < 64; off <<= 1) {
      uint32_t x = __shfl_up(p2, off);
      if (lane >= off) p2 += x;
    }
    wrank[t] = carry_s + p2 - v;
  }
  __syncthreads();
  for (int o = t; o < OUTK * 4; o += 256) out[o] = 0.0f;
  __syncthreads();
  for (int r = t; r < (int)TOPK; r += 256) {
    unsigned long long w =
        ((unsigned long long)keep32[2 * (r >> 6) + 1] << 32) | keep32[2 * (r >> 6)];
    int b = r & 63;
    if ((w >> b) & 1ull) {
      uint32_t rank = wrank[r >> 6] + (uint32_t)__popcll(w & ((1ull << b) - 1ull));
      if (rank < OUTK) {
        float4 bx = selbox[r];
        out[rank * 4 + 0] = bx.x;
        out[rank * 4 + 1] = bx.y;
        out[rank * 4 + 2] = bx.z;
        out[rank * 4 + 3] = bx.w;
      }
    }
  }
}

// ---------------- launch ----------------
extern "C" void kernel_launch(void* const* d_in, const int* in_sizes, int n_in,
                              void* d_out, int out_size, void* d_ws, size_t ws_size,
                              hipStream_t stream) {
  const float* cls    = (const float*)d_in[0];
  const float* reg    = (const float*)d_in[1];
  const float* anchor = (const float*)d_in[2];
  float* out = (float*)d_out;
  char* ws = (char*)d_ws;

  float4*   roi     = (float4*)(ws + OFF_ROI);
  uint32_t* key     = (uint32_t*)(ws + OFF_KEY);
  uint32_t* hist16  = (uint32_t*)(ws + OFF_HIST16);
  uint32_t* hists   = (uint32_t*)(ws + OFF_HISTS);
  int*      scal    = (int*)(ws + OFF_SCAL);
  uint32_t* rcnt    = (uint32_t*)(ws + OFF_RCNT);
  unsigned long long* sortbuf = (unsigned long long*)(ws + OFF_SORT);
  float4*   selbox  = (float4*)(ws + OFF_SELBOX);
  unsigned long long* diag = (unsigned long long*)(ws + OFF_DIAG);
  unsigned short* rows = (unsigned short*)(ws + OFF_ROWS);

  int blocks = (NN + 255) / 256;
  k_init<<<INIT_BLOCKS, 256, 0, stream>>>(ws);
  k_decode<<<blocks, 256, 0, stream>>>(cls, reg, anchor, roi, key, hist16);
  k_hsum<<<65536 / 256, 256, 0, stream>>>(hist16, hists);
  k_scan16<<<1, 1024, 0, stream>>>(hists, scal);
  k_compact<<<blocks, 256, 0, stream>>>(key, scal, sortbuf);
  k_sortA<<<NCHUNK, 256, 0, stream>>>(sortbuf);
  k_sortB<<<SORTN / 256, 256, 0, stream>>>(sortbuf, roi, selbox);
  k_mask<<<dim3(KW, KW), 64, 0, stream>>>(selbox, diag, rcnt, rows);
  k_seq<<<1, 256, 0, stream>>>(diag, rcnt, rows, scal, selbox, out);
}

// Round 16
// 109.220 us; speedup vs baseline: 2.5869x; 1.2135x over previous
//
#include <hip/hip_runtime.h>
#include <stdint.h>

#pragma clang fp contract(off)

#define NN    300000
#define TOPK  6000u
#define KW    94
#define KPAD  6016
#define SORTN 8192
#define NCHUNK 16
#define CSZ   512
#define OUTK  300
#define ECAP2 2048
#define NREP  8

// ---------------- workspace layout (bytes) ----------------
static constexpr size_t OFF_ROI    = 0;                                   // NN*16
static constexpr size_t OFF_KEY    = OFF_ROI + (size_t)NN * 16;           // NN*4
static constexpr size_t OFF_HIST16 = ((OFF_KEY + (size_t)NN * 4 + 255) & ~(size_t)255); // NREP*65536*4
static constexpr size_t OFF_SCAL   = OFF_HIST16 + (size_t)NREP * 65536 * 4; // 256 B
static constexpr size_t OFF_ECNT   = OFF_SCAL + 256;                      // 94*4 pad 512
static constexpr size_t ZERO_BYTES = (OFF_ECNT + 512) - OFF_HIST16;
static constexpr size_t OFF_HISTS  = OFF_ECNT + 512;                      // 65536*4
static constexpr size_t OFF_BSUM   = OFF_HISTS + 65536 * 4;               // 256*4 pad 1024
static constexpr size_t OFF_SORT   = OFF_BSUM + 1024;                     // SORTN*8
static constexpr size_t OFF_SELBOX = OFF_SORT + (size_t)SORTN * 8;        // KPAD*16
static constexpr size_t OFF_DIAG   = ((OFF_SELBOX + (size_t)KPAD * 16 + 255) & ~(size_t)255); // KPAD*8
static constexpr size_t OFF_ELIST  = OFF_DIAG + (size_t)KPAD * 8;         // KW*ECAP2*4 ~= 770KB

// scal[]: [0]=P16 bin, [3]=compact counter, [4]=valid total

static constexpr uint32_t ZG = (uint32_t)(ZERO_BYTES / 16);
static constexpr uint32_t SG = (uint32_t)(SORTN * 8 / 16);
static constexpr uint32_t INIT_BLOCKS = (ZG + SG + 255) / 256;

__device__ __forceinline__ uint32_t score_key(float s) {
  uint32_t u = __float_as_uint(s);
  u = (u >> 31) ? ~u : (u | 0x80000000u);
  return ~u;
}
__device__ __forceinline__ uint32_t hslot(uint32_t b) { return __brev(b) >> 16; }

// ---------------- 0. workspace init ----------------
__global__ void __launch_bounds__(256) k_init(char* __restrict__ ws) {
  uint32_t idx = blockIdx.x * 256 + threadIdx.x;
  if (idx < ZG) {
    ((uint4*)(ws + OFF_HIST16))[idx] = make_uint4(0u, 0u, 0u, 0u);
  } else if (idx < ZG + SG) {
    ((uint4*)(ws + OFF_SORT))[idx - ZG] = make_uint4(~0u, ~0u, ~0u, ~0u);
  }
}

// ---------------- 1. decode + key + replicated 16-bit histogram ----------------
__global__ void k_decode(const float* __restrict__ cls, const float* __restrict__ reg,
                         const float* __restrict__ anchor, float4* __restrict__ roi,
                         uint32_t* __restrict__ key, uint32_t* __restrict__ hist16) {
  int i = blockIdx.x * blockDim.x + threadIdx.x;
  if (i >= NN) return;
  float c0 = cls[2 * i], c1 = cls[2 * i + 1];
  float m  = fmaxf(c0, c1);
  float a0 = c0 - m, a1 = c1 - m;
  float tn = fminf(a0, a1);
  float e  = (float)exp((double)tn);
  float e0 = (a0 == 0.0f) ? 1.0f : e;
  float e1 = (a1 == 0.0f) ? 1.0f : e;
  float s  = e1 / (e0 + e1);

  float4 a = ((const float4*)anchor)[i];
  float acx = (a.x + a.z) * 0.5f;
  float acy = (a.y + a.w) * 0.5f;
  float aw  = a.z - a.x;
  float ah  = a.w - a.y;
  float4 r = ((const float4*)reg)[i];
  float cx = r.x * aw + acx;
  float cy = r.y * ah + acy;
  float w  = (float)exp((double)r.z) * aw;
  float h  = (float)exp((double)r.w) * ah;
  float x1 = cx - w * 0.5f, y1 = cy - h * 0.5f;
  float x2 = cx + w * 0.5f, y2 = cy + h * 0.5f;
  x1 = fminf(fmaxf(x1, 0.0f), 1.0f);
  y1 = fminf(fmaxf(y1, 0.0f), 1.0f);
  x2 = fminf(fmaxf(x2, 0.0f), 1.0f);
  y2 = fminf(fmaxf(y2, 0.0f), 1.0f);
  float ws_ = x2 - x1, hs_ = y2 - y1;
  bool valid = (hs_ >= 0.001f) && (ws_ >= 0.001f);
  float msc = valid ? s : -__builtin_inff();
  uint32_t kk = score_key(msc);

  roi[i] = make_float4(x1, y1, x2, y2);
  key[i] = kk;
  if (valid) atomicAdd(&hist16[((blockIdx.x & (NREP - 1)) << 16) + hslot(kk >> 16)], 1u);
}

// ---------------- 1b. reduce replicas (linear bin) + coarse block sums ----------------
__global__ void __launch_bounds__(256) k_hsum(const uint32_t* __restrict__ hist16,
                                              uint32_t* __restrict__ hists,
                                              uint32_t* __restrict__ bsum) {
  __shared__ uint32_t red[256];
  int t = threadIdx.x;
  int b = blockIdx.x * 256 + t;            // linear bin
  uint32_t slot = hslot((uint32_t)b);      // scattered reads (L2-resident)
  uint32_t s = 0;
#pragma unroll
  for (int r = 0; r < NREP; r++) s += hist16[(r << 16) + slot];
  hists[b] = s;                            // coalesced write, bin-ordered
  red[t] = s;
  __syncthreads();
  for (int off = 128; off > 0; off >>= 1) {
    if (t < off) red[t] += red[t + off];
    __syncthreads();
  }
  if (t == 0) bsum[blockIdx.x] = red[0];
}

// ---------------- 2. tiny hierarchical scan: coarse 256 -> one 256-bin refine ------
__global__ void __launch_bounds__(256) k_scanS(const uint32_t* __restrict__ hists,
                                               const uint32_t* __restrict__ bsum,
                                               int* __restrict__ scal) {
  __shared__ uint32_t cum[256];
  __shared__ int Bs;
  int t = threadIdx.x;
  uint32_t v = bsum[t];
  cum[t] = v;
  if (t == 0) Bs = 256;
  __syncthreads();
  for (int off = 1; off < 256; off <<= 1) {
    uint32_t x = (t >= off) ? cum[t - off] : 0;
    __syncthreads();
    cum[t] += x;
    __syncthreads();
  }
  if (t == 255) scal[4] = (int)cum[255];           // total valid
  if (cum[t] >= TOPK && (t == 0 || cum[t - 1] < TOPK)) Bs = t;
  __syncthreads();
  int B = Bs;
  if (B == 256) { if (t == 0) scal[0] = 65535; return; }  // total < TOPK: take all
  uint32_t cumbase = (B > 0) ? cum[B - 1] : 0;
  __syncthreads();
  uint32_t h2 = hists[B * 256 + t];
  cum[t] = h2;
  __syncthreads();
  for (int off = 1; off < 256; off <<= 1) {
    uint32_t x = (t >= off) ? cum[t - off] : 0;
    __syncthreads();
    cum[t] += x;
    __syncthreads();
  }
  uint32_t cc = cumbase + cum[t];
  uint32_t cp = cumbase + cum[t] - h2;
  if (cc >= TOPK && cp < TOPK) scal[0] = B * 256 + t;
}

// ---------------- 4. compact candidates: prefix16 <= P16 ----------------
__global__ void k_compact(const uint32_t* __restrict__ key, int* __restrict__ scal,
                          unsigned long long* __restrict__ sortbuf) {
  __shared__ int lcnt, lbase;
  int t = threadIdx.x;
  int i = blockIdx.x * blockDim.x + t;
  if (t == 0) lcnt = 0;
  __syncthreads();
  bool sel = false;
  uint32_t kk = 0;
  int my = 0;
  if (i < NN) {
    uint32_t P = (uint32_t)scal[0];
    kk = key[i];
    if ((kk >> 16) <= P) { sel = true; my = atomicAdd(&lcnt, 1); }
  }
  __syncthreads();
  if (t == 0 && lcnt > 0) lbase = atomicAdd(&scal[3], lcnt);
  __syncthreads();
  if (sel) {
    int pos = lbase + my;
    if (pos < SORTN) sortbuf[pos] = (((unsigned long long)kk) << 32) | (uint32_t)i;
  }
}

// ---------------- 5a. per-chunk bitonic sort ----------------
__global__ void __launch_bounds__(256) k_sortA(unsigned long long* __restrict__ sortbuf) {
  __shared__ unsigned long long sm[CSZ];
  int t = threadIdx.x;
  unsigned long long* chunk = sortbuf + (size_t)blockIdx.x * CSZ;
  sm[t] = chunk[t];
  sm[t + 256] = chunk[t + 256];
  __syncthreads();
  for (int k = 2; k <= CSZ; k <<= 1) {
    for (int j = k >> 1; j > 0; j >>= 1) {
      int i1 = ((t & ~(j - 1)) << 1) | (t & (j - 1));
      int i2 = i1 | j;
      bool up = ((i1 & k) == 0);
      unsigned long long a = sm[i1], b = sm[i2];
      if ((a > b) == up) { sm[i1] = b; sm[i2] = a; }
      __syncthreads();
    }
  }
  chunk[t] = sm[t];
  chunk[t + 256] = sm[t + 256];
}

// ---------------- 5b. stable multi-merge rank + scatter ----------------
__global__ void __launch_bounds__(256) k_sortB(const unsigned long long* __restrict__ sortbuf,
                                               const float4* __restrict__ roi,
                                               float4* __restrict__ selbox) {
  int g = blockIdx.x * 256 + threadIdx.x;
  int c = g >> 9, p = g & (CSZ - 1);
  unsigned long long val = sortbuf[g];
  int rank = p;
  for (int c2 = 0; c2 < NCHUNK; c2++) {
    if (c2 == c) continue;
    const unsigned long long* base = sortbuf + ((size_t)c2 << 9);
    bool le = (c2 < c);
    int pos = 0;
#pragma unroll
    for (int s = CSZ; s > 0; s >>= 1) {
      if (pos + s <= CSZ) {
        unsigned long long v = base[pos + s - 1];
        if (le ? (v <= val) : (v < val)) pos += s;
      }
    }
    rank += pos;
  }
  if (rank < (int)TOPK) {
    selbox[rank] = roi[(uint32_t)val];
  } else if (rank < KPAD) {
    selbox[rank] = make_float4(0.f, 0.f, 0.f, 0.f);
  }
}

// ---------------- 6. suppression: dense diag + per-WORD global entry lists --------
// Inter-word entries appended to elist[word_of_i][..] (wave-aggregated atomic,
// R6's proven pattern). Within-word order is irrelevant: the word pass tests
// all of word c's entries against the same resolved keep word and ORs into
// pend - order-independent, deterministic.
__global__ void __launch_bounds__(64) k_mask(const float4* __restrict__ selbox,
                                             unsigned long long* __restrict__ diag,
                                             uint32_t* __restrict__ ecnt,
                                             uint32_t* __restrict__ elist) {
  int bi = blockIdx.x, bj = blockIdx.y;
  if (bj < bi) return;
  int t = threadIdx.x;
  __shared__ float4 jb[64];
  __shared__ float  ja[64];
  int j0 = bj * 64;
  float4 cb = selbox[j0 + t];
  jb[t] = cb;
  ja[t] = (cb.z - cb.x) * (cb.w - cb.y);
  __syncthreads();
  int i = bi * 64 + t;
  unsigned long long word = 0;
  if (i < (int)TOPK) {
    float4 bi4 = selbox[i];
    float ai = (bi4.z - bi4.x) * (bi4.w - bi4.y);
    for (int jj = 0; jj < 64; jj++) {
      int j = j0 + jj;
      float4 bb = jb[jj];
      float ltx = fmaxf(bi4.x, bb.x), lty = fmaxf(bi4.y, bb.y);
      float rbx = fminf(bi4.z, bb.z), rby = fminf(bi4.w, bb.w);
      float wx = fmaxf(rbx - ltx, 0.0f), wy = fmaxf(rby - lty, 0.0f);
      float inter = wx * wy;
      float iou = inter / (ai + ja[jj] - inter + 1e-9f);
      if (iou > 0.7f && j > i && j < (int)TOPK) word |= (1ull << jj);
    }
  }
  if (bi == bj) {
    diag[i] = word;
    return;
  }
  // sparse append to word bi's list: wave prefix + one atomic per block
  uint32_t cnt = (uint32_t)__popcll(word);
  uint32_t pre = cnt;
#pragma unroll
  for (int off = 1; off < 64; off <<= 1) {
    uint32_t v = __shfl_up(pre, off);
    if (t >= off) pre += v;
  }
  uint32_t total = __shfl(pre, 63);
  if (total == 0) return;
  uint32_t excl = pre - cnt;
  uint32_t base;
  if (t == 0) base = atomicAdd(&ecnt[bi], total);
  base = __shfl(base, 0);
  unsigned long long rem = word;
  uint32_t k = 0;
  while (rem) {
    int jj = (int)__builtin_ctzll(rem);
    rem &= rem - 1;
    uint32_t pos = base + excl + k;
    k++;
    if (pos < ECAP2) elist[(size_t)bi * ECAP2 + pos] = ((uint32_t)i << 16) | (uint32_t)(j0 + jj);
  }
}

// ---------------- 7. greedy keep: word-ordered pass, early exit, NO gather --------
// Entries already per-word in global elist (k_mask). Per word c: one in-chain
// LDS pend read; diag row + word's entries prefetched one word ahead from
// global (out of chain). Early exit at cum >= OUTK (prefix closure, R15).
// Typically reads only ~8 words' data - the old 48KB/E-wide gather is gone.
__global__ void __launch_bounds__(256) k_seq(const unsigned long long* __restrict__ diag,
                                             const uint32_t* __restrict__ ecnt,
                                             const uint32_t* __restrict__ elist,
                                             const int* __restrict__ scal,
                                             const float4* __restrict__ selbox,
                                             float* __restrict__ out) {
  __shared__ uint32_t pend32[2 * KW];
  __shared__ uint32_t keep32[2 * KW];
  __shared__ uint32_t wcnt_s[KW], wrank[KW], carry_s;
  const int t = threadIdx.x, lane = t & 63;

  if (t < 2 * KW) pend32[t] = 0;
  __syncthreads();

  if (t < 64) {
    // per-lane registers: ecnt for words lane and 64+lane (clamped)
    uint32_t ec0 = ecnt[lane];
    ec0 = (ec0 > ECAP2) ? ECAP2 : ec0;
    uint32_t ec1 = 0;
    if (64 + lane < KW) {
      ec1 = ecnt[64 + lane];
      ec1 = (ec1 > ECAP2) ? ECAP2 : ec1;
    }
    int V = scal[4];
    if (V > (int)TOPK) V = (int)TOPK;

    // prologue: word 0
    unsigned long long mb = diag[lane];
    uint32_t cw = __builtin_amdgcn_readlane(ec0, 0);
    uint32_t en0 = elist[lane];
    uint32_t en1 = elist[64 + lane];

    uint32_t cum = 0;
    int cut = KW - 1;
    for (int c = 0; c < KW; c++) {
      // prefetch word c+1 (global, out of chain)
      unsigned long long mbn = 0;
      uint32_t cwn = 0, en0n = 0, en1n = 0;
      if (c + 1 < KW) {
        mbn = diag[(c + 1) * 64 + lane];
        cwn = (c + 1 < 64) ? __builtin_amdgcn_readlane(ec0, c + 1)
                           : __builtin_amdgcn_readlane(ec1, c + 1 - 64);
        en0n = elist[(size_t)(c + 1) * ECAP2 + lane];
        en1n = elist[(size_t)(c + 1) * ECAP2 + 64 + lane];
      }
      // the one in-chain LDS read: pend for word c (uniform -> broadcast)
      uint32_t plo = pend32[2 * c], phi = pend32[2 * c + 1];
      int d = V - c * 64;
      unsigned long long vinit =
          (d <= 0) ? 0ull : ((d >= 64) ? ~0ull : ((1ull << d) - 1));
      unsigned long long w = vinit & ~(((unsigned long long)phi << 32) | plo);
      // intra-word resolve (register diag, usually 0 iterations)
      unsigned long long sup = __ballot(mb != 0);
      unsigned long long rem = w & sup;
      while (rem) {
        int b = (int)__builtin_ctzll(rem);
        uint32_t mlo = __builtin_amdgcn_readlane((uint32_t)mb, b);
        uint32_t mhi = __builtin_amdgcn_readlane((uint32_t)(mb >> 32), b);
        w &= ~(((unsigned long long)mhi << 32) | mlo);
        rem = (b >= 63) ? 0ull : (w & sup & (~0ull << (b + 1)));
      }
      if (lane == 0) {
        keep32[2 * c] = (uint32_t)w;
        keep32[2 * c + 1] = (uint32_t)(w >> 32);
      }
      // early exit (prefix closure): later words only yield ranks >= OUTK
      cum += (uint32_t)__popcll(w);
      if (cum >= OUTK) { cut = c; break; }
      // apply word c's entries: lane-parallel, fire-and-forget OR into pend
      if ((uint32_t)lane < cw) {
        uint32_t i = en0 >> 16, j = en0 & 0xFFFFu;
        if ((w >> (i & 63)) & 1ull) atomicOr(&pend32[j >> 5], 1u << (j & 31));
      }
      if ((uint32_t)(64 + lane) < cw) {
        uint32_t i = en1 >> 16, j = en1 & 0xFFFFu;
        if ((w >> (i & 63)) & 1ull) atomicOr(&pend32[j >> 5], 1u << (j & 31));
      }
      for (uint32_t k = 128 + (uint32_t)lane; k < cw; k += 64) {  // rare overflow
        uint32_t e = elist[(size_t)c * ECAP2 + k];
        uint32_t i = e >> 16, j = e & 0xFFFFu;
        if ((w >> (i & 63)) & 1ull) atomicOr(&pend32[j >> 5], 1u << (j & 31));
      }
      mb = mbn; cw = cwn; en0 = en0n; en1 = en1n;
    }
    // zero keep words beyond the cutoff
    for (int wz = cut + 1 + lane; wz < KW; wz += 64) {
      keep32[2 * wz] = 0;
      keep32[2 * wz + 1] = 0;
    }
  }
  __syncthreads();

  // parallel rank + output
  if (t < KW)
    wcnt_s[t] = (uint32_t)(__popc(keep32[2 * t]) + __popc(keep32[2 * t + 1]));
  __syncthreads();
  if (t < 64) {
    uint32_t v = wcnt_s[t], p2 = v;
#pragma unroll
    for (int off = 1; off < 64; off <<= 1) {
      uint32_t x = __shfl_up(p2, off);
      if (lane >= off) p2 += x;
    }
    wrank[t] = p2 - v;
    if (t == 63) carry_s = p2;
  }
  __syncthreads();
  if (t >= 64 && t < KW) {
    uint32_t v = wcnt_s[t], p2 = v;
#pragma unroll
    for (int off = 1; off < 64; off <<= 1) {
      uint32_t x = __shfl_up(p2, off);
      if (lane >= off) p2 += x;
    }
    wrank[t] = carry_s + p2 - v;
  }
  __syncthreads();
  for (int o = t; o < OUTK * 4; o += 256) out[o] = 0.0f;
  __syncthreads();
  for (int r = t; r < (int)TOPK; r += 256) {
    unsigned long long w =
        ((unsigned long long)keep32[2 * (r >> 6) + 1] << 32) | keep32[2 * (r >> 6)];
    int b = r & 63;
    if ((w >> b) & 1ull) {
      uint32_t rank = wrank[r >> 6] + (uint32_t)__popcll(w & ((1ull << b) - 1ull));
      if (rank < OUTK) {
        float4 bx = selbox[r];
        out[rank * 4 + 0] = bx.x;
        out[rank * 4 + 1] = bx.y;
        out[rank * 4 + 2] = bx.z;
        out[rank * 4 + 3] = bx.w;
      }
    }
  }
}

// ---------------- launch ----------------
extern "C" void kernel_launch(void* const* d_in, const int* in_sizes, int n_in,
                              void* d_out, int out_size, void* d_ws, size_t ws_size,
                              hipStream_t stream) {
  const float* cls    = (const float*)d_in[0];
  const float* reg    = (const float*)d_in[1];
  const float* anchor = (const float*)d_in[2];
  float* out = (float*)d_out;
  char* ws = (char*)d_ws;

  float4*   roi     = (float4*)(ws + OFF_ROI);
  uint32_t* key     = (uint32_t*)(ws + OFF_KEY);
  uint32_t* hist16  = (uint32_t*)(ws + OFF_HIST16);
  uint32_t* hists   = (uint32_t*)(ws + OFF_HISTS);
  uint32_t* bsum    = (uint32_t*)(ws + OFF_BSUM);
  int*      scal    = (int*)(ws + OFF_SCAL);
  uint32_t* ecnt    = (uint32_t*)(ws + OFF_ECNT);
  unsigned long long* sortbuf = (unsigned long long*)(ws + OFF_SORT);
  float4*   selbox  = (float4*)(ws + OFF_SELBOX);
  unsigned long long* diag = (unsigned long long*)(ws + OFF_DIAG);
  uint32_t* elist   = (uint32_t*)(ws + OFF_ELIST);

  int blocks = (NN + 255) / 256;
  k_init<<<INIT_BLOCKS, 256, 0, stream>>>(ws);
  k_decode<<<blocks, 256, 0, stream>>>(cls, reg, anchor, roi, key, hist16);
  k_hsum<<<65536 / 256, 256, 0, stream>>>(hist16, hists, bsum);
  k_scanS<<<1, 256, 0, stream>>>(hists, bsum, scal);
  k_compact<<<blocks, 256, 0, stream>>>(key, scal, sortbuf);
  k_sortA<<<NCHUNK, 256, 0, stream>>>(sortbuf);
  k_sortB<<<SORTN / 256, 256, 0, stream>>>(sortbuf, roi, selbox);
  k_mask<<<dim3(KW, KW), 64, 0, stream>>>(selbox, diag, ecnt, elist);
  k_seq<<<1, 256, 0, stream>>>(diag, ecnt, elist, scal, selbox, out);
}